// Round 6
// baseline (555.045 us; speedup 1.0000x reference)
//
#include <hip/hip_runtime.h>
#include <hip/hip_bf16.h>
#include <stdint.h>

// Shapes (hard-coded for this problem)
#define T_  4
#define B_  64
#define C_  384
#define N_  196        // H*W = 14*14
#define NH  8
#define DH  48
#define TB_ (T_*B_)          // 256
#define R_  (T_*B_*N_)       // 50176 pixels total
#define NW  12               // 384 bits -> 12 u32 words per pixel
#define P_  12544            // B_*N_ pixels per timestep
#define NCH 66               // pixel chunks of 768 (12 u64); 66*768 >= 50176
#define KG_ 17               // gram k-groups (4 chunks each)
#define PIX 16               // pixels per conv_lif_t block

typedef float f32x2 __attribute__((ext_vector_type(2)));

// ---------------------------------------------------------------------------
// K0: transpose all 4 weights W[o][c] -> WT[m][c][o]
__global__ void transpose_w4(const float* __restrict__ s0, const float* __restrict__ s1,
                             const float* __restrict__ s2, const float* __restrict__ s3,
                             float* __restrict__ dst){
    int m = blockIdx.y;
    const float* src = (m==0)?s0:(m==1)?s1:(m==2)?s2:s3;
    int idx = blockIdx.x*256 + threadIdx.x;
    if (idx >= C_*C_) return;
    int o = idx % C_, c = idx / C_;
    dst[(size_t)m*C_*C_ + idx] = src[o*C_ + c];
}

// ---------------------------------------------------------------------------
// K1: pre-LIF on raw x -> spike bitmask [t][b][n][12 words]
__global__ __launch_bounds__(256) void pre_lif(const float* __restrict__ x,
                                               uint32_t* __restrict__ maskXS){
    int b = blockIdx.x / NW;
    int w = blockIdx.x % NW;
    int n = threadIdx.x;
    if (n >= N_) return;
    float v[32];
#pragma unroll
    for (int j=0;j<32;j++) v[j] = 0.f;
#pragma unroll
    for (int t=0;t<T_;t++){
        uint32_t word = 0;
#pragma unroll
        for (int j=0;j<32;j++){
            int c = w*32 + j;
            float xv = x[((size_t)(t*B_+b)*C_ + c)*N_ + n];
            v[j] = v[j] + (xv - v[j])*0.5f;
            if (v[j] >= 1.0f){ word |= (1u<<j); v[j] = 0.f; }
        }
        maskXS[((size_t)(t*B_+b)*N_ + n)*NW + w] = word;
    }
}

// ---------------------------------------------------------------------------
// K2: bit-transpose masks: [pixel][384 bits] -> maskT[chunk][c][12 u64]
__global__ __launch_bounds__(256) void bit_transpose(const uint32_t* __restrict__ mask,
                                                     unsigned long long* __restrict__ maskT){
    int gw = blockIdx.x*4 + (threadIdx.x>>6);      // 0..791
    int lane = threadIdx.x & 63;
    int kc = gw/12, kw = gw%12;
    uint32_t mwv[12];
#pragma unroll
    for (int w=0;w<12;w++) mwv[w]=0u;
    if (gw < 784){
        int pix = gw*64 + lane;
        const uint4* m4 = (const uint4*)(mask + (size_t)pix*NW);
        uint4 a=m4[0], b=m4[1], c=m4[2];
        mwv[0]=a.x; mwv[1]=a.y; mwv[2]=a.z; mwv[3]=a.w;
        mwv[4]=b.x; mwv[5]=b.y; mwv[6]=b.z; mwv[7]=b.w;
        mwv[8]=c.x; mwv[9]=c.y; mwv[10]=c.z; mwv[11]=c.w;
    }
#pragma unroll
    for (int w=0; w<12; w++){
        uint32_t word = mwv[w];
#pragma unroll
        for (int j=0; j<32; j++){
            unsigned long long bal = __ballot((int)((word>>j)&1u));
            if (lane == 0)
                maskT[((size_t)kc*C_ + (w*32+j))*12 + kw] = bal;
        }
    }
}

// ---------------------------------------------------------------------------
// K3: Gram partials: G[c][c'] = popcount co-occurrence. grid (KG_, 6 rg, 8 cg).
__global__ __launch_bounds__(256) void gram(const unsigned long long* __restrict__ maskT,
                                            unsigned int* __restrict__ Gpart){
    __shared__ unsigned int tile[64][49];
    int tid = threadIdx.x, wave = tid>>6, lane = tid&63;
    int kg = blockIdx.x, rg = blockIdx.y, cg = blockIdx.z;
    for (int i=tid; i<64*49; i+=256) ((unsigned int*)tile)[i] = 0u;
    __syncthreads();
    int kc = kg*4 + wave;
    if (kc < NCH){
        const uint4* rp = (const uint4*)(maskT + ((size_t)kc*C_ + rg*64 + lane)*12);
        uint32_t row[24];
#pragma unroll
        for (int q=0;q<6;q++){
            uint4 a = rp[q];
            row[4*q]=a.x; row[4*q+1]=a.y; row[4*q+2]=a.z; row[4*q+3]=a.w;
        }
        for (int cc=0; cc<48; cc++){
            const uint4* cp = (const uint4*)(maskT + ((size_t)kc*C_ + cg*48 + cc)*12);
            uint32_t col[24];
#pragma unroll
            for (int q=0;q<6;q++){
                uint4 a = cp[q];
                col[4*q]=a.x; col[4*q+1]=a.y; col[4*q+2]=a.z; col[4*q+3]=a.w;
            }
            unsigned int s = 0;
#pragma unroll
            for (int q=0;q<24;q++) s += (unsigned int)__popc(row[q]&col[q]);
            atomicAdd(&tile[lane][cc], s);
        }
    }
    __syncthreads();
    unsigned int* out = Gpart + (size_t)kg*C_*C_;
    for (int i=tid; i<64*48; i+=256){
        int r = i/48, cc = i%48;
        out[(size_t)(rg*64+r)*C_ + cg*48 + cc] = tile[r][cc];
    }
}

// K3b: reduce partials -> Gf (float, exact ints)
__global__ __launch_bounds__(256) void gram_reduce(const unsigned int* __restrict__ Gpart,
                                                   float* __restrict__ Gf){
    int e = blockIdx.x*256 + threadIdx.x;           // < 147456
    unsigned int s = 0;
#pragma unroll
    for (int k=0;k<KG_;k++) s += Gpart[(size_t)k*C_*C_ + e];
    Gf[e] = (float)s;
}

// ---------------------------------------------------------------------------
// K4: BN scale/shift from Gram: sum[o]=sum_c cnt[c] w[c], sumsq[o]=w^T G w.
__global__ __launch_bounds__(384) void bn_from_gram(const float* __restrict__ Gf,
        const float* __restrict__ WTall,
        const float* __restrict__ g0, const float* __restrict__ b0,
        const float* __restrict__ g1, const float* __restrict__ b1,
        const float* __restrict__ g2, const float* __restrict__ b2,
        float* __restrict__ scaleOut, float* __restrict__ shiftOut, int wtBase){
    __shared__ float w4[384][4];
    __shared__ float sred[8][6];
    int t = threadIdx.x, wave = t>>6, lane = t&63;
    int br = blockIdx.y;
    const float* WT = WTall + (size_t)(wtBase+br)*C_*C_;
    int o0 = blockIdx.x*4;
    float4 wv = *(const float4*)(WT + (size_t)t*C_ + o0);
    w4[t][0]=wv.x; w4[t][1]=wv.y; w4[t][2]=wv.z; w4[t][3]=wv.w;
    __syncthreads();
    float h0=0.f,h1=0.f,h2=0.f,h3=0.f;
#pragma unroll 4
    for (int c=0;c<C_;c++){
        float gv = Gf[(size_t)c*C_ + t];
        float4 wc = *(const float4*)&w4[c][0];
        h0 += gv*wc.x; h1 += gv*wc.y; h2 += gv*wc.z; h3 += gv*wc.w;
    }
    float cnt = Gf[(size_t)t*C_ + t];
    float p0=wv.x*h0, p1=wv.y*h1, p2=wv.z*h2, p3=wv.w*h3;
    float q0=cnt*wv.x, q1=cnt*wv.y, q2=cnt*wv.z, q3=cnt*wv.w;
#pragma unroll
    for (int off=32; off>0; off>>=1){
        p0+=__shfl_down(p0,off); p1+=__shfl_down(p1,off);
        p2+=__shfl_down(p2,off); p3+=__shfl_down(p3,off);
        q0+=__shfl_down(q0,off); q1+=__shfl_down(q1,off);
        q2+=__shfl_down(q2,off); q3+=__shfl_down(q3,off);
    }
    if (lane == 0){
        sred[0][wave]=p0; sred[1][wave]=p1; sred[2][wave]=p2; sred[3][wave]=p3;
        sred[4][wave]=q0; sred[5][wave]=q1; sred[6][wave]=q2; sred[7][wave]=q3;
    }
    __syncthreads();
    if (t < 4){
        const float* g  = (br==0)?g0:(br==1)?g1:g2;
        const float* bb = (br==0)?b0:(br==1)?b1:b2;
        float ss = ((sred[t][0]+sred[t][1])+(sred[t][2]+sred[t][3]))+(sred[t][4]+sred[t][5]);
        float sm = ((sred[4+t][0]+sred[4+t][1])+(sred[4+t][2]+sred[4+t][3]))+(sred[4+t][4]+sred[4+t][5]);
        float m   = sm / (float)R_;
        float var = ss / (float)R_ - m*m;
        float sc  = g[o0+t] / sqrtf(var + 1e-5f);
        scaleOut[br*C_ + o0+t] = sc;
        shiftOut[br*C_ + o0+t] = bb[o0+t] - m*sc;
    }
}

// ---------------------------------------------------------------------------
// K5: LDS-tiled sparse conv + BN + LIF + pack, all 3 branches.
// Block = 16 pixels x 4 t (64 instances); wave owns 4 pixels; lane owns
// o = 6*lane..6*lane+5. 12 chunks of 32 channels staged in LDS (48 KB).
__global__ __launch_bounds__(256, 4) void conv_lif_t(const uint32_t* __restrict__ mask,
        const float* __restrict__ WTall,
        const float* __restrict__ scaleAll, const float* __restrict__ shiftAll,
        uint32_t* __restrict__ moQ, uint32_t* __restrict__ moK, uint32_t* __restrict__ moV){
    __shared__ float wchunk[32*C_];                // 48 KB; reused as pack area
    __shared__ uint32_t lm[PIX][4][12];            // 3 KB instance masks
    int tid = threadIdx.x, wave = tid>>6, lane = tid&63;
    int pix0 = blockIdx.x*PIX;

    // stage instance masks (coalesced per t)
    for (int i = tid; i < PIX*4*12; i += 256){
        int t = i / (PIX*12), r = i % (PIX*12);
        int p = r / 12, w = r % 12;
        lm[p][t][w] = mask[((size_t)t*P_ + pix0 + p)*NW + w];
    }

    int pbase = wave*4;
    for (int br = 0; br < 3; ++br){
        float y[4][4][6];
#pragma unroll
        for (int p=0;p<4;p++)
#pragma unroll
            for (int tt=0;tt<4;tt++)
#pragma unroll
                for (int j=0;j<6;j++) y[p][tt][j] = 0.f;

        const float* WT = WTall + (size_t)br*C_*C_;
        for (int ch = 0; ch < 12; ++ch){
            __syncthreads();                       // previous LDS use complete
            const float4* src = (const float4*)(WT + (size_t)ch*32*C_);
            float4* dst = (float4*)wchunk;
#pragma unroll
            for (int k = 0; k < 12; ++k)
                dst[tid + k*256] = src[tid + k*256];
            __syncthreads();
#pragma unroll
            for (int p = 0; p < 4; ++p){
#pragma unroll
                for (int tt = 0; tt < 4; ++tt){
                    uint32_t bits = lm[pbase+p][tt][ch];
                    while (bits){
                        int c = __builtin_ctz(bits); bits &= bits - 1;
                        const float* col = wchunk + c*C_ + lane*6;
                        f32x2 a = *(const f32x2*)(col);
                        f32x2 b = *(const f32x2*)(col+2);
                        f32x2 d = *(const f32x2*)(col+4);
                        y[p][tt][0] += a.x; y[p][tt][1] += a.y;
                        y[p][tt][2] += b.x; y[p][tt][3] += b.y;
                        y[p][tt][4] += d.x; y[p][tt][5] += d.y;
                    }
                }
            }
        }
        __syncthreads();                           // all waves done reading wchunk
        uint32_t* mypack = ((uint32_t*)wchunk) + wave*192;   // 16 inst x 12 words
        for (int i = lane; i < 192; i += 64) mypack[i] = 0u;
        __syncthreads();

        int o0 = lane*6, w0 = o0 >> 5, shf = o0 & 31;
#pragma unroll
        for (int p = 0; p < 4; ++p){
            float vv[6] = {0.f,0.f,0.f,0.f,0.f,0.f};
#pragma unroll
            for (int tt = 0; tt < 4; ++tt){
                uint32_t bits6 = 0;
#pragma unroll
                for (int j = 0; j < 6; ++j){
                    float sc = scaleAll[br*C_ + o0 + j];
                    float sh = shiftAll[br*C_ + o0 + j];
                    float val = y[p][tt][j]*sc + sh;
                    vv[j] = vv[j] + (val - vv[j])*0.5f;
                    if (vv[j] >= 1.0f){ bits6 |= (1u<<j); vv[j] = 0.f; }
                }
                int inst = p*4 + tt;
                atomicOr(&mypack[inst*12 + w0], bits6 << shf);
                if (shf > 26)
                    atomicOr(&mypack[inst*12 + w0 + 1], bits6 >> (32-shf));
            }
        }
        __syncthreads();                           // pack complete
        uint32_t* mo = (br==0)?moQ:(br==1)?moK:moV;
        if (lane < 48){
            int inst = lane >> 2;                  // wait: need 16 inst x 3 quads
            int q = lane % 3;                      // placeholder (fixed below)
        }
        // 16 instances x 3 uint4 stores = 48 lanes: lane -> (inst, quad)
        if (lane < 48){
            int inst = lane / 3, q = lane % 3;
            int p = inst >> 2, tt = inst & 3;
            uint4 val = *(const uint4*)&mypack[inst*12 + q*4];
            size_t g = ((size_t)tt*P_ + pix0 + pbase + p)*NW + q*4;
            *(uint4*)(mo + g) = val;
        }
    }
}

// ---------------------------------------------------------------------------
// K6: spiking attention + attn_lif via C = K^T V (exact integers).
__global__ __launch_bounds__(256) void attention_lif(const uint32_t* __restrict__ mq,
                                                     const uint32_t* __restrict__ mk,
                                                     const uint32_t* __restrict__ mv,
                                                     uint16_t* __restrict__ mo){
    __shared__ unsigned long long kT[DH][4];
    __shared__ unsigned long long vT[DH][4];
    __shared__ uint32_t Cp[DH*25];           // u16-pair packed C, row stride 25

    int h = blockIdx.x & 7;
    int b = blockIdx.x >> 3;
    int tid = threadIdx.x, wv = tid>>6, lane = tid&63;
    int sw  = (h*DH) >> 5;
    int shf = (h*DH) & 31;                   // 0 or 16

    float vm[DH];
#pragma unroll
    for (int d=0;d<DH;d++) vm[d] = 0.f;

    for (int t=0;t<T_;t++){
        int tb = t*B_ + b;
        unsigned long long q = 0, kk = 0, vvv = 0;
        if (tid < N_){
            const uint32_t* pq = mq + ((size_t)tb*N_ + tid)*NW + sw;
            const uint32_t* pk = mk + ((size_t)tb*N_ + tid)*NW + sw;
            const uint32_t* pv = mv + ((size_t)tb*N_ + tid)*NW + sw;
            unsigned long long lo, hi;
            lo = pq[0]; hi = pq[1];
            q   = (shf ? ((lo>>16) | (hi<<16)) : (lo | (hi<<32))) & 0xFFFFFFFFFFFFULL;
            lo = pk[0]; hi = pk[1];
            kk  = (shf ? ((lo>>16) | (hi<<16)) : (lo | (hi<<32))) & 0xFFFFFFFFFFFFULL;
            lo = pv[0]; hi = pv[1];
            vvv = (shf ? ((lo>>16) | (hi<<16)) : (lo | (hi<<32))) & 0xFFFFFFFFFFFFULL;
        }
#pragma unroll 1
        for (int d=0; d<DH; d++){
            unsigned long long bk_ = __ballot((int)((kk >>d)&1ull));
            unsigned long long bv_ = __ballot((int)((vvv>>d)&1ull));
            if (lane == 0){ kT[d][wv] = bk_; vT[d][wv] = bv_; }
        }
        __syncthreads();

        if (tid < 240){
            int j  = tid / 5;
            int dg = tid % 5;
            int d0 = dg*10;
            int d1 = (dg==4) ? 48 : d0+10;
            unsigned long long ka=kT[j][0], kb=kT[j][1], kc=kT[j][2], kd=kT[j][3];
            for (int d=d0; d<d1; d+=2){
                uint32_t c0 = (uint32_t)(__popcll(ka&vT[d][0]) + __popcll(kb&vT[d][1])
                            + __popcll(kc&vT[d][2]) + __popcll(kd&vT[d][3]));
                uint32_t c1 = (uint32_t)(__popcll(ka&vT[d+1][0]) + __popcll(kb&vT[d+1][1])
                            + __popcll(kc&vT[d+1][2]) + __popcll(kd&vT[d+1][3]));
                Cp[j*25 + (d>>1)] = c0 | (c1<<16);
            }
        }
        __syncthreads();

        if (tid < N_){
            uint32_t acc[24];
#pragma unroll
            for (int p=0;p<24;p++) acc[p] = 0u;
            unsigned long long qb = q;
            while (qb){
                int j = __builtin_ctzll(qb); qb &= qb-1;
                const uint32_t* row = &Cp[j*25];
#pragma unroll
                for (int p=0;p<24;p++) acc[p] += row[p];
            }
            unsigned long long sp = 0;
#pragma unroll
            for (int d=0; d<DH; d++){
                uint32_t a = (d&1) ? (acc[d>>1]>>16) : (acc[d>>1]&0xFFFFu);
                float o = 0.125f*(float)a;
                vm[d] = vm[d] + (o - vm[d])*0.5f;
                if (vm[d] >= 0.5f){ sp |= (1ull<<d); vm[d] = 0.f; }
            }
            size_t rec = ((size_t)tb*N_ + tid)*24 + 3*h;   // u16 index
            mo[rec]   = (uint16_t)(sp);
            mo[rec+1] = (uint16_t)(sp >> 16);
            mo[rec+2] = (uint16_t)(sp >> 32);
        }
        __syncthreads();
    }
}

// ---------------------------------------------------------------------------
// K7: proj conv + BN normalize + transposed write via LDS tile.
__global__ __launch_bounds__(256) void proj_out(const uint32_t* __restrict__ mask,
                                                const float* __restrict__ WT,
                                                const float* __restrict__ scale,
                                                const float* __restrict__ shift,
                                                float* __restrict__ out){
    __shared__ float tile[192][98];
    __shared__ uint16_t lst[4][400];
    int bid = blockIdx.x;
    int tb = bid>>2, nh = (bid>>1)&1, ch = bid&1;
    int n0 = nh*98, c0 = ch*192;
    int tid = threadIdx.x, wave = tid>>6, lane = tid&63;
    float sc[3], sh[3];
#pragma unroll
    for (int i=0;i<3;i++){
        sc[i] = scale[c0+(i<<6)+lane];
        sh[i] = shift[c0+(i<<6)+lane];
    }
    for (int p=wave; p<98; p+=4){
        size_t pix = (size_t)tb*N_ + n0 + p;
        const uint4* m4 = (const uint4*)(mask + pix*NW);
        uint4 ma = m4[0], mb = m4[1], mc = m4[2];
        uint32_t mwv[12] = {ma.x,ma.y,ma.z,ma.w, mb.x,mb.y,mb.z,mb.w, mc.x,mc.y,mc.z,mc.w};
        int cnt = 0;
#pragma unroll
        for (int w=0;w<12;w++) cnt += __popc(mwv[w]);
        if (lane == 0){
            int k = 0;
#pragma unroll
            for (int w=0;w<12;w++){
                uint32_t bits = mwv[w];
                while (bits){
                    lst[wave][k++] = (uint16_t)((w<<5) + __builtin_ctz(bits));
                    bits &= bits - 1;
                }
            }
        }
        float ya[3]={0,0,0}, yb[3]={0,0,0}, yc[3]={0,0,0}, yd[3]={0,0,0};
        int i = 0;
        for (; i+3 < cnt; i += 4){
            ushort4 cs = *(const ushort4*)&lst[wave][i];
            const float* q0 = WT + (size_t)cs.x*C_ + c0 + lane;
            const float* q1 = WT + (size_t)cs.y*C_ + c0 + lane;
            const float* q2 = WT + (size_t)cs.z*C_ + c0 + lane;
            const float* q3 = WT + (size_t)cs.w*C_ + c0 + lane;
#pragma unroll
            for (int j=0;j<3;j++){
                ya[j] += q0[j<<6]; yb[j] += q1[j<<6];
                yc[j] += q2[j<<6]; yd[j] += q3[j<<6];
            }
        }
        for (; i < cnt; ++i){
            int c = lst[wave][i];
            const float* q0 = WT + (size_t)c*C_ + c0 + lane;
#pragma unroll
            for (int j=0;j<3;j++) ya[j] += q0[j<<6];
        }
#pragma unroll
        for (int j=0;j<3;j++)
            tile[(j<<6)+lane][p] = ((ya[j]+yb[j])+(yc[j]+yd[j]))*sc[j] + sh[j];
    }
    __syncthreads();
    for (int r=wave; r<192; r+=4){
        if (lane < 49){
            f32x2 tv = *(const f32x2*)&tile[r][2*lane];
            *(f32x2*)(out + ((size_t)tb*C_ + c0 + r)*N_ + n0 + 2*lane) = tv;
        }
    }
}

// ---------------------------------------------------------------------------
extern "C" void kernel_launch(void* const* d_in, const int* in_sizes, int n_in,
                              void* d_out, int out_size, void* d_ws, size_t ws_size,
                              hipStream_t stream) {
    const float* x  = (const float*)d_in[0];
    const float* Wq = (const float*)d_in[1];
    const float* Wk = (const float*)d_in[2];
    const float* Wv = (const float*)d_in[3];
    const float* Wp = (const float*)d_in[4];
    const float* gq = (const float*)d_in[5];
    const float* bq = (const float*)d_in[6];
    const float* gk = (const float*)d_in[7];
    const float* bk = (const float*)d_in[8];
    const float* gv = (const float*)d_in[9];
    const float* bv = (const float*)d_in[10];
    const float* gp = (const float*)d_in[11];
    const float* bp = (const float*)d_in[12];

    // workspace carve (~25 MB)
    char* w = (char*)d_ws;
    size_t off = 0;
    uint32_t* maskXS = (uint32_t*)(w + off); off += (size_t)R_*NW*4;   // 2.41 MB each
    uint32_t* maskQ  = (uint32_t*)(w + off); off += (size_t)R_*NW*4;
    uint32_t* maskK  = (uint32_t*)(w + off); off += (size_t)R_*NW*4;
    uint32_t* maskV  = (uint32_t*)(w + off); off += (size_t)R_*NW*4;
    float* WTall = (float*)(w + off); off += (size_t)4*C_*C_*4;        // 2.36 MB
    unsigned long long* maskT = (unsigned long long*)(w + off); off += (size_t)NCH*C_*12*8; // 2.43 MB
    unsigned int* Gpart = (unsigned int*)(w + off); off += (size_t)KG_*C_*C_*4;             // 10.0 MB
    float* Gf = (float*)(w + off); off += (size_t)C_*C_*4;             // 0.59 MB
    float* scaleB = (float*)(w + off); off += (size_t)4*C_*4;
    float* shiftB = (float*)(w + off); off += (size_t)4*C_*4;
    uint32_t* maskOL = maskXS;      // alias: XS dead after conv_lif_t

    transpose_w4<<<dim3((C_*C_+255)/256, 4),256,0,stream>>>(Wq, Wk, Wv, Wp, WTall);

    pre_lif<<<B_*NW,256,0,stream>>>(x, maskXS);

    // stats for q,k,v branches via one shared Gram of maskXS
    bit_transpose<<<198,256,0,stream>>>(maskXS, maskT);
    gram<<<dim3(KG_,6,8),256,0,stream>>>(maskT, Gpart);
    gram_reduce<<<576,256,0,stream>>>(Gpart, Gf);
    bn_from_gram<<<dim3(96,3),384,0,stream>>>(Gf, WTall, gq,bq, gk,bk, gv,bv,
                                              scaleB, shiftB, 0);

    conv_lif_t<<<P_/PIX,256,0,stream>>>(maskXS, WTall, scaleB, shiftB,
                                        maskQ, maskK, maskV);

    attention_lif<<<B_*NH,256,0,stream>>>(maskQ, maskK, maskV, (uint16_t*)maskOL);

    // proj stats via Gram of maskOL
    bit_transpose<<<198,256,0,stream>>>(maskOL, maskT);
    gram<<<dim3(KG_,6,8),256,0,stream>>>(maskT, Gpart);
    gram_reduce<<<576,256,0,stream>>>(Gpart, Gf);
    bn_from_gram<<<dim3(96,1),384,0,stream>>>(Gf, WTall, gp,bp, gp,bp, gp,bp,
                                              scaleB + 3*C_, shiftB + 3*C_, 3);

    proj_out<<<TB_*4,256,0,stream>>>(maskOL, WTall + (size_t)3*C_*C_,
                                     scaleB + 3*C_, shiftB + 3*C_, (float*)d_out);
}

// Round 7
// 418.902 us; speedup vs baseline: 1.3250x; 1.3250x over previous
//
#include <hip/hip_runtime.h>
#include <hip/hip_bf16.h>
#include <stdint.h>

// Shapes (hard-coded for this problem)
#define T_  4
#define B_  64
#define C_  384
#define N_  196        // H*W = 14*14
#define NH  8
#define DH  48
#define TB_ (T_*B_)          // 256
#define R_  (T_*B_*N_)       // 50176 pixels total
#define NW  12               // 384 bits -> 12 u32 words per pixel
#define P_  12544            // B_*N_ pixels per timestep
#define NCH 66               // pixel chunks of 768 (12 u64); 66*768 >= 50176
#define KG_ 17               // gram k-groups (4 chunks each)

typedef float f32x2 __attribute__((ext_vector_type(2)));

// ---------------------------------------------------------------------------
// K0: transpose all 4 weights W[o][c] -> WT[m][c][o]
__global__ void transpose_w4(const float* __restrict__ s0, const float* __restrict__ s1,
                             const float* __restrict__ s2, const float* __restrict__ s3,
                             float* __restrict__ dst){
    int m = blockIdx.y;
    const float* src = (m==0)?s0:(m==1)?s1:(m==2)?s2:s3;
    int idx = blockIdx.x*256 + threadIdx.x;
    if (idx >= C_*C_) return;
    int o = idx % C_, c = idx / C_;
    dst[(size_t)m*C_*C_ + idx] = src[o*C_ + c];
}

// ---------------------------------------------------------------------------
// K1: pre-LIF on raw x -> spike bitmask [t][b][n][12 words]
__global__ __launch_bounds__(256) void pre_lif(const float* __restrict__ x,
                                               uint32_t* __restrict__ maskXS){
    int b = blockIdx.x / NW;
    int w = blockIdx.x % NW;
    int n = threadIdx.x;
    if (n >= N_) return;
    float v[32];
#pragma unroll
    for (int j=0;j<32;j++) v[j] = 0.f;
#pragma unroll
    for (int t=0;t<T_;t++){
        uint32_t word = 0;
#pragma unroll
        for (int j=0;j<32;j++){
            int c = w*32 + j;
            float xv = x[((size_t)(t*B_+b)*C_ + c)*N_ + n];
            v[j] = v[j] + (xv - v[j])*0.5f;
            if (v[j] >= 1.0f){ word |= (1u<<j); v[j] = 0.f; }
        }
        maskXS[((size_t)(t*B_+b)*N_ + n)*NW + w] = word;
    }
}

// ---------------------------------------------------------------------------
// K2: bit-transpose masks: [pixel][384 bits] -> maskT[chunk][c][12 u64]
__global__ __launch_bounds__(256) void bit_transpose(const uint32_t* __restrict__ mask,
                                                     unsigned long long* __restrict__ maskT){
    int gw = blockIdx.x*4 + (threadIdx.x>>6);      // 0..791
    int lane = threadIdx.x & 63;
    int kc = gw/12, kw = gw%12;
    uint32_t mwv[12];
#pragma unroll
    for (int w=0;w<12;w++) mwv[w]=0u;
    if (gw < 784){
        int pix = gw*64 + lane;
        const uint4* m4 = (const uint4*)(mask + (size_t)pix*NW);
        uint4 a=m4[0], b=m4[1], c=m4[2];
        mwv[0]=a.x; mwv[1]=a.y; mwv[2]=a.z; mwv[3]=a.w;
        mwv[4]=b.x; mwv[5]=b.y; mwv[6]=b.z; mwv[7]=b.w;
        mwv[8]=c.x; mwv[9]=c.y; mwv[10]=c.z; mwv[11]=c.w;
    }
#pragma unroll
    for (int w=0; w<12; w++){
        uint32_t word = mwv[w];
#pragma unroll
        for (int j=0; j<32; j++){
            unsigned long long bal = __ballot((int)((word>>j)&1u));
            if (lane == 0)
                maskT[((size_t)kc*C_ + (w*32+j))*12 + kw] = bal;
        }
    }
}

// ---------------------------------------------------------------------------
// K3: Gram partials: G[c][c'] = popcount co-occurrence. grid (KG_, 6 rg, 8 cg).
__global__ __launch_bounds__(256) void gram(const unsigned long long* __restrict__ maskT,
                                            unsigned int* __restrict__ Gpart){
    __shared__ unsigned int tile[64][49];
    int tid = threadIdx.x, wave = tid>>6, lane = tid&63;
    int kg = blockIdx.x, rg = blockIdx.y, cg = blockIdx.z;
    for (int i=tid; i<64*49; i+=256) ((unsigned int*)tile)[i] = 0u;
    __syncthreads();
    int kc = kg*4 + wave;
    if (kc < NCH){
        const uint4* rp = (const uint4*)(maskT + ((size_t)kc*C_ + rg*64 + lane)*12);
        uint32_t row[24];
#pragma unroll
        for (int q=0;q<6;q++){
            uint4 a = rp[q];
            row[4*q]=a.x; row[4*q+1]=a.y; row[4*q+2]=a.z; row[4*q+3]=a.w;
        }
        for (int cc=0; cc<48; cc++){
            const uint4* cp = (const uint4*)(maskT + ((size_t)kc*C_ + cg*48 + cc)*12);
            uint32_t col[24];
#pragma unroll
            for (int q=0;q<6;q++){
                uint4 a = cp[q];
                col[4*q]=a.x; col[4*q+1]=a.y; col[4*q+2]=a.z; col[4*q+3]=a.w;
            }
            unsigned int s = 0;
#pragma unroll
            for (int q=0;q<24;q++) s += (unsigned int)__popc(row[q]&col[q]);
            atomicAdd(&tile[lane][cc], s);
        }
    }
    __syncthreads();
    unsigned int* out = Gpart + (size_t)kg*C_*C_;
    for (int i=tid; i<64*48; i+=256){
        int r = i/48, cc = i%48;
        out[(size_t)(rg*64+r)*C_ + cg*48 + cc] = tile[r][cc];
    }
}

// K3b: reduce partials -> Gf (float, exact ints)
__global__ __launch_bounds__(256) void gram_reduce(const unsigned int* __restrict__ Gpart,
                                                   float* __restrict__ Gf){
    int e = blockIdx.x*256 + threadIdx.x;           // < 147456
    unsigned int s = 0;
#pragma unroll
    for (int k=0;k<KG_;k++) s += Gpart[(size_t)k*C_*C_ + e];
    Gf[e] = (float)s;
}

// ---------------------------------------------------------------------------
// K4: BN scale/shift from Gram: sum[o]=sum_c cnt[c] w[c], sumsq[o]=w^T G w.
__global__ __launch_bounds__(384) void bn_from_gram(const float* __restrict__ Gf,
        const float* __restrict__ WTall,
        const float* __restrict__ g0, const float* __restrict__ b0,
        const float* __restrict__ g1, const float* __restrict__ b1,
        const float* __restrict__ g2, const float* __restrict__ b2,
        float* __restrict__ scaleOut, float* __restrict__ shiftOut, int wtBase){
    __shared__ float w4[384][4];
    __shared__ float sred[8][6];
    int t = threadIdx.x, wave = t>>6, lane = t&63;
    int br = blockIdx.y;
    const float* WT = WTall + (size_t)(wtBase+br)*C_*C_;
    int o0 = blockIdx.x*4;
    float4 wv = *(const float4*)(WT + (size_t)t*C_ + o0);
    w4[t][0]=wv.x; w4[t][1]=wv.y; w4[t][2]=wv.z; w4[t][3]=wv.w;
    __syncthreads();
    float h0=0.f,h1=0.f,h2=0.f,h3=0.f;
#pragma unroll 4
    for (int c=0;c<C_;c++){
        float gv = Gf[(size_t)c*C_ + t];
        float4 wc = *(const float4*)&w4[c][0];
        h0 += gv*wc.x; h1 += gv*wc.y; h2 += gv*wc.z; h3 += gv*wc.w;
    }
    float cnt = Gf[(size_t)t*C_ + t];
    float p0=wv.x*h0, p1=wv.y*h1, p2=wv.z*h2, p3=wv.w*h3;
    float q0=cnt*wv.x, q1=cnt*wv.y, q2=cnt*wv.z, q3=cnt*wv.w;
#pragma unroll
    for (int off=32; off>0; off>>=1){
        p0+=__shfl_down(p0,off); p1+=__shfl_down(p1,off);
        p2+=__shfl_down(p2,off); p3+=__shfl_down(p3,off);
        q0+=__shfl_down(q0,off); q1+=__shfl_down(q1,off);
        q2+=__shfl_down(q2,off); q3+=__shfl_down(q3,off);
    }
    if (lane == 0){
        sred[0][wave]=p0; sred[1][wave]=p1; sred[2][wave]=p2; sred[3][wave]=p3;
        sred[4][wave]=q0; sred[5][wave]=q1; sred[6][wave]=q2; sred[7][wave]=q3;
    }
    __syncthreads();
    if (t < 4){
        const float* g  = (br==0)?g0:(br==1)?g1:g2;
        const float* bb = (br==0)?b0:(br==1)?b1:b2;
        float ss = ((sred[t][0]+sred[t][1])+(sred[t][2]+sred[t][3]))+(sred[t][4]+sred[t][5]);
        float sm = ((sred[4+t][0]+sred[4+t][1])+(sred[4+t][2]+sred[4+t][3]))+(sred[4+t][4]+sred[4+t][5]);
        float m   = sm / (float)R_;
        float var = ss / (float)R_ - m*m;
        float sc  = g[o0+t] / sqrtf(var + 1e-5f);
        scaleOut[br*C_ + o0+t] = sc;
        shiftOut[br*C_ + o0+t] = bb[o0+t] - m*sc;
    }
}

// ---------------------------------------------------------------------------
// K5: sparse conv + fused BN + LIF + pack, ALL 3 branches per wave.
// Wave = one (b,n) pixel; t loop; active-channel list built cooperatively ONCE
// per (pixel,t) and reused by the 3 branch gather loops (x4 unrolled, 24
// outstanding L2 loads). Lane owns o = 64*i + lane (i<6) for ballot packing.
__global__ __launch_bounds__(256) void conv_lif3(const uint32_t* __restrict__ mask,
        const float* __restrict__ WTall,
        const float* __restrict__ scaleAll, const float* __restrict__ shiftAll,
        uint32_t* __restrict__ moQ, uint32_t* __restrict__ moK, uint32_t* __restrict__ moV){
    __shared__ uint16_t lst[4][416];
    __shared__ float scLDS[3*C_];
    __shared__ float shLDS[3*C_];
    int tid = threadIdx.x, wave = tid>>6, lane = tid&63;
    int pix0 = blockIdx.x*4 + wave;
    for (int i=tid; i<3*C_; i+=256){ scLDS[i]=scaleAll[i]; shLDS[i]=shiftAll[i]; }
    __syncthreads();

    float v0[6]={0,0,0,0,0,0}, v1[6]={0,0,0,0,0,0}, v2[6]={0,0,0,0,0,0};
    for (int t=0;t<T_;t++){
        size_t pix = (size_t)t*P_ + pix0;
        const uint4* m4 = (const uint4*)(mask + pix*NW);
        uint4 ma = m4[0], mb = m4[1], mc = m4[2];       // wave-uniform
        uint32_t mwv[12] = {ma.x,ma.y,ma.z,ma.w, mb.x,mb.y,mb.z,mb.w, mc.x,mc.y,mc.z,mc.w};
        int cnt = 0;
#pragma unroll
        for (int w=0;w<12;w++) cnt += __popc(mwv[w]);
        // cooperative list build: lane w<12 emits word w's channels at prefix off
        if (lane < 12){
            int off = 0;
            uint32_t mybits = 0;
#pragma unroll
            for (int w=0;w<12;w++){
                if (w < lane) off += __popc(mwv[w]);
                if (w == lane) mybits = mwv[w];
            }
            while (mybits){
                lst[wave][off++] = (uint16_t)((lane<<5) + __builtin_ctz(mybits));
                mybits &= mybits - 1;
            }
        }
        __syncthreads();

#pragma unroll
        for (int br=0; br<3; ++br){
            const float* WT = WTall + (size_t)br*C_*C_ + lane;
            float ya[6]={0,0,0,0,0,0}, yb[6]={0,0,0,0,0,0};
            float yc[6]={0,0,0,0,0,0}, yd[6]={0,0,0,0,0,0};
            int i = 0;
            for (; i+3 < cnt; i += 4){
                ushort4 cs = *(const ushort4*)&lst[wave][i];
                const float* q0 = WT + (size_t)cs.x*C_;
                const float* q1 = WT + (size_t)cs.y*C_;
                const float* q2 = WT + (size_t)cs.z*C_;
                const float* q3 = WT + (size_t)cs.w*C_;
#pragma unroll
                for (int j=0;j<6;j++){
                    ya[j] += q0[j<<6]; yb[j] += q1[j<<6];
                    yc[j] += q2[j<<6]; yd[j] += q3[j<<6];
                }
            }
            for (; i < cnt; ++i){
                int c = lst[wave][i];
                const float* q0 = WT + (size_t)c*C_;
#pragma unroll
                for (int j=0;j<6;j++) ya[j] += q0[j<<6];
            }
            float* vs = (br==0)?v0:(br==1)?v1:v2;
            uint32_t words[12];
#pragma unroll
            for (int j=0;j<6;j++){
                int o = (j<<6) + lane;
                float val = ((ya[j]+yb[j])+(yc[j]+yd[j]))*scLDS[br*C_+o] + shLDS[br*C_+o];
                float vv = vs[j];
                vv = vv + (val - vv)*0.5f;
                int s = (vv >= 1.0f);
                unsigned long long bal = __ballot(s);
                if (s) vv = 0.f;
                vs[j] = vv;
                words[2*j]   = (uint32_t)bal;
                words[2*j+1] = (uint32_t)(bal>>32);
            }
            if (lane == 0){
                uint32_t* mo = (br==0)?moQ:(br==1)?moK:moV;
                uint4* o4 = (uint4*)(mo + pix*NW);
                o4[0] = make_uint4(words[0],words[1],words[2],words[3]);
                o4[1] = make_uint4(words[4],words[5],words[6],words[7]);
                o4[2] = make_uint4(words[8],words[9],words[10],words[11]);
            }
        }
        __syncthreads();     // lst reused next t
    }
}

// ---------------------------------------------------------------------------
// K6: spiking attention + attn_lif via C = K^T V (exact integers).
__global__ __launch_bounds__(256) void attention_lif(const uint32_t* __restrict__ mq,
                                                     const uint32_t* __restrict__ mk,
                                                     const uint32_t* __restrict__ mv,
                                                     uint16_t* __restrict__ mo){
    __shared__ unsigned long long kT[DH][4];
    __shared__ unsigned long long vT[DH][4];
    __shared__ uint32_t Cp[DH*25];           // u16-pair packed C, row stride 25

    int h = blockIdx.x & 7;
    int b = blockIdx.x >> 3;
    int tid = threadIdx.x, wv = tid>>6, lane = tid&63;
    int sw  = (h*DH) >> 5;
    int shf = (h*DH) & 31;                   // 0 or 16

    float vm[DH];
#pragma unroll
    for (int d=0;d<DH;d++) vm[d] = 0.f;

    for (int t=0;t<T_;t++){
        int tb = t*B_ + b;
        unsigned long long q = 0, kk = 0, vvv = 0;
        if (tid < N_){
            const uint32_t* pq = mq + ((size_t)tb*N_ + tid)*NW + sw;
            const uint32_t* pk = mk + ((size_t)tb*N_ + tid)*NW + sw;
            const uint32_t* pv = mv + ((size_t)tb*N_ + tid)*NW + sw;
            unsigned long long lo, hi;
            lo = pq[0]; hi = pq[1];
            q   = (shf ? ((lo>>16) | (hi<<16)) : (lo | (hi<<32))) & 0xFFFFFFFFFFFFULL;
            lo = pk[0]; hi = pk[1];
            kk  = (shf ? ((lo>>16) | (hi<<16)) : (lo | (hi<<32))) & 0xFFFFFFFFFFFFULL;
            lo = pv[0]; hi = pv[1];
            vvv = (shf ? ((lo>>16) | (hi<<16)) : (lo | (hi<<32))) & 0xFFFFFFFFFFFFULL;
        }
#pragma unroll 1
        for (int d=0; d<DH; d++){
            unsigned long long bk_ = __ballot((int)((kk >>d)&1ull));
            unsigned long long bv_ = __ballot((int)((vvv>>d)&1ull));
            if (lane == 0){ kT[d][wv] = bk_; vT[d][wv] = bv_; }
        }
        __syncthreads();

        if (tid < 240){
            int j  = tid / 5;
            int dg = tid % 5;
            int d0 = dg*10;
            int d1 = (dg==4) ? 48 : d0+10;
            unsigned long long ka=kT[j][0], kb=kT[j][1], kc=kT[j][2], kd=kT[j][3];
            for (int d=d0; d<d1; d+=2){
                uint32_t c0 = (uint32_t)(__popcll(ka&vT[d][0]) + __popcll(kb&vT[d][1])
                            + __popcll(kc&vT[d][2]) + __popcll(kd&vT[d][3]));
                uint32_t c1 = (uint32_t)(__popcll(ka&vT[d+1][0]) + __popcll(kb&vT[d+1][1])
                            + __popcll(kc&vT[d+1][2]) + __popcll(kd&vT[d+1][3]));
                Cp[j*25 + (d>>1)] = c0 | (c1<<16);
            }
        }
        __syncthreads();

        if (tid < N_){
            uint32_t acc[24];
#pragma unroll
            for (int p=0;p<24;p++) acc[p] = 0u;
            unsigned long long qb = q;
            while (qb){
                int j = __builtin_ctzll(qb); qb &= qb-1;
                const uint32_t* row = &Cp[j*25];
#pragma unroll
                for (int p=0;p<24;p++) acc[p] += row[p];
            }
            unsigned long long sp = 0;
#pragma unroll
            for (int d=0; d<DH; d++){
                uint32_t a = (d&1) ? (acc[d>>1]>>16) : (acc[d>>1]&0xFFFFu);
                float o = 0.125f*(float)a;
                vm[d] = vm[d] + (o - vm[d])*0.5f;
                if (vm[d] >= 0.5f){ sp |= (1ull<<d); vm[d] = 0.f; }
            }
            size_t rec = ((size_t)tb*N_ + tid)*24 + 3*h;   // u16 index
            mo[rec]   = (uint16_t)(sp);
            mo[rec+1] = (uint16_t)(sp >> 16);
            mo[rec+2] = (uint16_t)(sp >> 32);
        }
        __syncthreads();
    }
}

// ---------------------------------------------------------------------------
// K7: proj conv + BN normalize + transposed write via LDS tile.
__global__ __launch_bounds__(256) void proj_out(const uint32_t* __restrict__ mask,
                                                const float* __restrict__ WT,
                                                const float* __restrict__ scale,
                                                const float* __restrict__ shift,
                                                float* __restrict__ out){
    __shared__ float tile[192][98];
    __shared__ uint16_t lst[4][400];
    int bid = blockIdx.x;
    int tb = bid>>2, nh = (bid>>1)&1, ch = bid&1;
    int n0 = nh*98, c0 = ch*192;
    int tid = threadIdx.x, wave = tid>>6, lane = tid&63;
    float sc[3], sh[3];
#pragma unroll
    for (int i=0;i<3;i++){
        sc[i] = scale[c0+(i<<6)+lane];
        sh[i] = shift[c0+(i<<6)+lane];
    }
    for (int p=wave; p<98; p+=4){
        size_t pix = (size_t)tb*N_ + n0 + p;
        const uint4* m4 = (const uint4*)(mask + pix*NW);
        uint4 ma = m4[0], mb = m4[1], mc = m4[2];
        uint32_t mwv[12] = {ma.x,ma.y,ma.z,ma.w, mb.x,mb.y,mb.z,mb.w, mc.x,mc.y,mc.z,mc.w};
        int cnt = 0;
#pragma unroll
        for (int w=0;w<12;w++) cnt += __popc(mwv[w]);
        if (lane == 0){
            int k = 0;
#pragma unroll
            for (int w=0;w<12;w++){
                uint32_t bits = mwv[w];
                while (bits){
                    lst[wave][k++] = (uint16_t)((w<<5) + __builtin_ctz(bits));
                    bits &= bits - 1;
                }
            }
        }
        float ya[3]={0,0,0}, yb[3]={0,0,0}, yc[3]={0,0,0}, yd[3]={0,0,0};
        int i = 0;
        for (; i+3 < cnt; i += 4){
            ushort4 cs = *(const ushort4*)&lst[wave][i];
            const float* q0 = WT + (size_t)cs.x*C_ + c0 + lane;
            const float* q1 = WT + (size_t)cs.y*C_ + c0 + lane;
            const float* q2 = WT + (size_t)cs.z*C_ + c0 + lane;
            const float* q3 = WT + (size_t)cs.w*C_ + c0 + lane;
#pragma unroll
            for (int j=0;j<3;j++){
                ya[j] += q0[j<<6]; yb[j] += q1[j<<6];
                yc[j] += q2[j<<6]; yd[j] += q3[j<<6];
            }
        }
        for (; i < cnt; ++i){
            int c = lst[wave][i];
            const float* q0 = WT + (size_t)c*C_ + c0 + lane;
#pragma unroll
            for (int j=0;j<3;j++) ya[j] += q0[j<<6];
        }
#pragma unroll
        for (int j=0;j<3;j++)
            tile[(j<<6)+lane][p] = ((ya[j]+yb[j])+(yc[j]+yd[j]))*sc[j] + sh[j];
    }
    __syncthreads();
    for (int r=wave; r<192; r+=4){
        if (lane < 49){
            f32x2 tv = *(const f32x2*)&tile[r][2*lane];
            *(f32x2*)(out + ((size_t)tb*C_ + c0 + r)*N_ + n0 + 2*lane) = tv;
        }
    }
}

// ---------------------------------------------------------------------------
extern "C" void kernel_launch(void* const* d_in, const int* in_sizes, int n_in,
                              void* d_out, int out_size, void* d_ws, size_t ws_size,
                              hipStream_t stream) {
    const float* x  = (const float*)d_in[0];
    const float* Wq = (const float*)d_in[1];
    const float* Wk = (const float*)d_in[2];
    const float* Wv = (const float*)d_in[3];
    const float* Wp = (const float*)d_in[4];
    const float* gq = (const float*)d_in[5];
    const float* bq = (const float*)d_in[6];
    const float* gk = (const float*)d_in[7];
    const float* bk = (const float*)d_in[8];
    const float* gv = (const float*)d_in[9];
    const float* bv = (const float*)d_in[10];
    const float* gp = (const float*)d_in[11];
    const float* bp = (const float*)d_in[12];

    // workspace carve (~25 MB)
    char* w = (char*)d_ws;
    size_t off = 0;
    uint32_t* maskXS = (uint32_t*)(w + off); off += (size_t)R_*NW*4;   // 2.41 MB each
    uint32_t* maskQ  = (uint32_t*)(w + off); off += (size_t)R_*NW*4;
    uint32_t* maskK  = (uint32_t*)(w + off); off += (size_t)R_*NW*4;
    uint32_t* maskV  = (uint32_t*)(w + off); off += (size_t)R_*NW*4;
    float* WTall = (float*)(w + off); off += (size_t)4*C_*C_*4;        // 2.36 MB
    unsigned long long* maskT = (unsigned long long*)(w + off); off += (size_t)NCH*C_*12*8; // 2.43 MB
    unsigned int* Gpart = (unsigned int*)(w + off); off += (size_t)KG_*C_*C_*4;             // 10.0 MB
    float* Gf = (float*)(w + off); off += (size_t)C_*C_*4;             // 0.59 MB
    float* scaleB = (float*)(w + off); off += (size_t)4*C_*4;
    float* shiftB = (float*)(w + off); off += (size_t)4*C_*4;
    uint32_t* maskOL = maskXS;      // alias: XS dead after conv_lif3

    transpose_w4<<<dim3((C_*C_+255)/256, 4),256,0,stream>>>(Wq, Wk, Wv, Wp, WTall);

    pre_lif<<<B_*NW,256,0,stream>>>(x, maskXS);

    // stats for q,k,v branches via one shared Gram of maskXS
    bit_transpose<<<198,256,0,stream>>>(maskXS, maskT);
    gram<<<dim3(KG_,6,8),256,0,stream>>>(maskT, Gpart);
    gram_reduce<<<576,256,0,stream>>>(Gpart, Gf);
    bn_from_gram<<<dim3(96,3),384,0,stream>>>(Gf, WTall, gq,bq, gk,bk, gv,bv,
                                              scaleB, shiftB, 0);

    conv_lif3<<<P_/4,256,0,stream>>>(maskXS, WTall, scaleB, shiftB,
                                     maskQ, maskK, maskV);

    attention_lif<<<B_*NH,256,0,stream>>>(maskQ, maskK, maskV, (uint16_t*)maskOL);

    // proj stats via Gram of maskOL
    bit_transpose<<<198,256,0,stream>>>(maskOL, maskT);
    gram<<<dim3(KG_,6,8),256,0,stream>>>(maskT, Gpart);
    gram_reduce<<<576,256,0,stream>>>(Gpart, Gf);
    bn_from_gram<<<dim3(96,1),384,0,stream>>>(Gf, WTall, gp,bp, gp,bp, gp,bp,
                                              scaleB + 3*C_, shiftB + 3*C_, 3);

    proj_out<<<TB_*4,256,0,stream>>>(maskOL, WTall + (size_t)3*C_*C_,
                                     scaleB + 3*C_, shiftB + 3*C_, (float*)d_out);
}

// Round 8
// 402.939 us; speedup vs baseline: 1.3775x; 1.0396x over previous
//
#include <hip/hip_runtime.h>
#include <hip/hip_bf16.h>
#include <stdint.h>

// Shapes (hard-coded for this problem)
#define T_  4
#define B_  64
#define C_  384
#define N_  196        // H*W = 14*14
#define NH  8
#define DH  48
#define TB_ (T_*B_)          // 256
#define R_  (T_*B_*N_)       // 50176 pixels total
#define NW  12               // 384 bits -> 12 u32 words per pixel
#define P_  12544            // B_*N_ pixels per timestep
#define NCH 66               // pixel chunks of 768 (12 u64); 66*768 >= 50176
#define KG_ 17               // gram k-groups (4 chunks each)

typedef float f32x2 __attribute__((ext_vector_type(2)));

// ---------------------------------------------------------------------------
// K0: transpose all 4 weights W[o][c] -> WT[m][c][o]
__global__ void transpose_w4(const float* __restrict__ s0, const float* __restrict__ s1,
                             const float* __restrict__ s2, const float* __restrict__ s3,
                             float* __restrict__ dst){
    int m = blockIdx.y;
    const float* src = (m==0)?s0:(m==1)?s1:(m==2)?s2:s3;
    int idx = blockIdx.x*256 + threadIdx.x;
    if (idx >= C_*C_) return;
    int o = idx % C_, c = idx / C_;
    dst[(size_t)m*C_*C_ + idx] = src[o*C_ + c];
}

// ---------------------------------------------------------------------------
// K1: pre-LIF on raw x -> spike bitmask [t][b][n][12 words]
__global__ __launch_bounds__(256) void pre_lif(const float* __restrict__ x,
                                               uint32_t* __restrict__ maskXS){
    int b = blockIdx.x / NW;
    int w = blockIdx.x % NW;
    int n = threadIdx.x;
    if (n >= N_) return;
    float v[32];
#pragma unroll
    for (int j=0;j<32;j++) v[j] = 0.f;
#pragma unroll
    for (int t=0;t<T_;t++){
        uint32_t word = 0;
#pragma unroll
        for (int j=0;j<32;j++){
            int c = w*32 + j;
            float xv = x[((size_t)(t*B_+b)*C_ + c)*N_ + n];
            v[j] = v[j] + (xv - v[j])*0.5f;
            if (v[j] >= 1.0f){ word |= (1u<<j); v[j] = 0.f; }
        }
        maskXS[((size_t)(t*B_+b)*N_ + n)*NW + w] = word;
    }
}

// ---------------------------------------------------------------------------
// K2: bit-transpose masks: [pixel][384 bits] -> maskT[chunk][c][12 u64]
__global__ __launch_bounds__(256) void bit_transpose(const uint32_t* __restrict__ mask,
                                                     unsigned long long* __restrict__ maskT){
    int gw = blockIdx.x*4 + (threadIdx.x>>6);      // 0..791
    int lane = threadIdx.x & 63;
    int kc = gw/12, kw = gw%12;
    uint32_t mwv[12];
#pragma unroll
    for (int w=0;w<12;w++) mwv[w]=0u;
    if (gw < 784){
        int pix = gw*64 + lane;
        const uint4* m4 = (const uint4*)(mask + (size_t)pix*NW);
        uint4 a=m4[0], b=m4[1], c=m4[2];
        mwv[0]=a.x; mwv[1]=a.y; mwv[2]=a.z; mwv[3]=a.w;
        mwv[4]=b.x; mwv[5]=b.y; mwv[6]=b.z; mwv[7]=b.w;
        mwv[8]=c.x; mwv[9]=c.y; mwv[10]=c.z; mwv[11]=c.w;
    }
#pragma unroll
    for (int w=0; w<12; w++){
        uint32_t word = mwv[w];
#pragma unroll
        for (int j=0; j<32; j++){
            unsigned long long bal = __ballot((int)((word>>j)&1u));
            if (lane == 0)
                maskT[((size_t)kc*C_ + (w*32+j))*12 + kw] = bal;
        }
    }
}

// ---------------------------------------------------------------------------
// K3: Gram: G[c][c'] popcount co-occurrence, atomically accumulated into
// global u32 Gu (exact, order-independent). grid (KG_, 6 rg, 8 cg).
__global__ __launch_bounds__(256) void gram(const unsigned long long* __restrict__ maskT,
                                            unsigned int* __restrict__ Gu){
    __shared__ unsigned int tile[64][49];
    int tid = threadIdx.x, wave = tid>>6, lane = tid&63;
    int kg = blockIdx.x, rg = blockIdx.y, cg = blockIdx.z;
    for (int i=tid; i<64*49; i+=256) ((unsigned int*)tile)[i] = 0u;
    __syncthreads();
    int kc = kg*4 + wave;
    if (kc < NCH){
        const uint4* rp = (const uint4*)(maskT + ((size_t)kc*C_ + rg*64 + lane)*12);
        uint32_t row[24];
#pragma unroll
        for (int q=0;q<6;q++){
            uint4 a = rp[q];
            row[4*q]=a.x; row[4*q+1]=a.y; row[4*q+2]=a.z; row[4*q+3]=a.w;
        }
        for (int cc=0; cc<48; cc++){
            const uint4* cp = (const uint4*)(maskT + ((size_t)kc*C_ + cg*48 + cc)*12);
            uint32_t col[24];
#pragma unroll
            for (int q=0;q<6;q++){
                uint4 a = cp[q];
                col[4*q]=a.x; col[4*q+1]=a.y; col[4*q+2]=a.z; col[4*q+3]=a.w;
            }
            unsigned int s = 0;
#pragma unroll
            for (int q=0;q<24;q++) s += (unsigned int)__popc(row[q]&col[q]);
            atomicAdd(&tile[lane][cc], s);
        }
    }
    __syncthreads();
    for (int i=tid; i<64*48; i+=256){
        int r = i/48, cc = i%48;
        unsigned int v = tile[r][cc];
        if (v) atomicAdd(&Gu[(size_t)(rg*64+r)*C_ + cg*48 + cc], v);
    }
}

// ---------------------------------------------------------------------------
// K4: BN scale/shift from Gram: sum[o]=sum_c cnt[c] w[c], sumsq[o]=w^T G w.
__global__ __launch_bounds__(384) void bn_from_gram(const unsigned int* __restrict__ Gu,
        const float* __restrict__ WTall,
        const float* __restrict__ g0, const float* __restrict__ b0,
        const float* __restrict__ g1, const float* __restrict__ b1,
        const float* __restrict__ g2, const float* __restrict__ b2,
        float* __restrict__ scaleOut, float* __restrict__ shiftOut, int wtBase){
    __shared__ float w4[384][4];
    __shared__ float sred[8][6];
    int t = threadIdx.x, wave = t>>6, lane = t&63;
    int br = blockIdx.y;
    const float* WT = WTall + (size_t)(wtBase+br)*C_*C_;
    int o0 = blockIdx.x*4;
    float4 wv = *(const float4*)(WT + (size_t)t*C_ + o0);
    w4[t][0]=wv.x; w4[t][1]=wv.y; w4[t][2]=wv.z; w4[t][3]=wv.w;
    __syncthreads();
    float h0=0.f,h1=0.f,h2=0.f,h3=0.f;
#pragma unroll 4
    for (int c=0;c<C_;c++){
        float gv = (float)Gu[(size_t)c*C_ + t];
        float4 wc = *(const float4*)&w4[c][0];
        h0 += gv*wc.x; h1 += gv*wc.y; h2 += gv*wc.z; h3 += gv*wc.w;
    }
    float cnt = (float)Gu[(size_t)t*C_ + t];
    float p0=wv.x*h0, p1=wv.y*h1, p2=wv.z*h2, p3=wv.w*h3;
    float q0=cnt*wv.x, q1=cnt*wv.y, q2=cnt*wv.z, q3=cnt*wv.w;
#pragma unroll
    for (int off=32; off>0; off>>=1){
        p0+=__shfl_down(p0,off); p1+=__shfl_down(p1,off);
        p2+=__shfl_down(p2,off); p3+=__shfl_down(p3,off);
        q0+=__shfl_down(q0,off); q1+=__shfl_down(q1,off);
        q2+=__shfl_down(q2,off); q3+=__shfl_down(q3,off);
    }
    if (lane == 0){
        sred[0][wave]=p0; sred[1][wave]=p1; sred[2][wave]=p2; sred[3][wave]=p3;
        sred[4][wave]=q0; sred[5][wave]=q1; sred[6][wave]=q2; sred[7][wave]=q3;
    }
    __syncthreads();
    if (t < 4){
        const float* g  = (br==0)?g0:(br==1)?g1:g2;
        const float* bb = (br==0)?b0:(br==1)?b1:b2;
        float ss = ((sred[t][0]+sred[t][1])+(sred[t][2]+sred[t][3]))+(sred[t][4]+sred[t][5]);
        float sm = ((sred[4+t][0]+sred[4+t][1])+(sred[4+t][2]+sred[4+t][3]))+(sred[4+t][4]+sred[4+t][5]);
        float m   = sm / (float)R_;
        float var = ss / (float)R_ - m*m;
        float sc  = g[o0+t] / sqrtf(var + 1e-5f);
        scaleOut[br*C_ + o0+t] = sc;
        shiftOut[br*C_ + o0+t] = bb[o0+t] - m*sc;
    }
}

// ---------------------------------------------------------------------------
// K5: sparse conv + fused BN + LIF + pack, ALL 3 branches per wave.
// (Round-7 version: L2-BW bound at ~36 TB/s — at the roofline for f32 gather.)
__global__ __launch_bounds__(256) void conv_lif3(const uint32_t* __restrict__ mask,
        const float* __restrict__ WTall,
        const float* __restrict__ scaleAll, const float* __restrict__ shiftAll,
        uint32_t* __restrict__ moQ, uint32_t* __restrict__ moK, uint32_t* __restrict__ moV){
    __shared__ uint16_t lst[4][416];
    __shared__ float scLDS[3*C_];
    __shared__ float shLDS[3*C_];
    int tid = threadIdx.x, wave = tid>>6, lane = tid&63;
    int pix0 = blockIdx.x*4 + wave;
    for (int i=tid; i<3*C_; i+=256){ scLDS[i]=scaleAll[i]; shLDS[i]=shiftAll[i]; }
    __syncthreads();

    float v0[6]={0,0,0,0,0,0}, v1[6]={0,0,0,0,0,0}, v2[6]={0,0,0,0,0,0};
    for (int t=0;t<T_;t++){
        size_t pix = (size_t)t*P_ + pix0;
        const uint4* m4 = (const uint4*)(mask + pix*NW);
        uint4 ma = m4[0], mb = m4[1], mc = m4[2];       // wave-uniform
        uint32_t mwv[12] = {ma.x,ma.y,ma.z,ma.w, mb.x,mb.y,mb.z,mb.w, mc.x,mc.y,mc.z,mc.w};
        int cnt = 0;
#pragma unroll
        for (int w=0;w<12;w++) cnt += __popc(mwv[w]);
        if (lane < 12){
            int off = 0;
            uint32_t mybits = 0;
#pragma unroll
            for (int w=0;w<12;w++){
                if (w < lane) off += __popc(mwv[w]);
                if (w == lane) mybits = mwv[w];
            }
            while (mybits){
                lst[wave][off++] = (uint16_t)((lane<<5) + __builtin_ctz(mybits));
                mybits &= mybits - 1;
            }
        }
        __syncthreads();

#pragma unroll
        for (int br=0; br<3; ++br){
            const float* WT = WTall + (size_t)br*C_*C_ + lane;
            float ya[6]={0,0,0,0,0,0}, yb[6]={0,0,0,0,0,0};
            float yc[6]={0,0,0,0,0,0}, yd[6]={0,0,0,0,0,0};
            int i = 0;
            for (; i+3 < cnt; i += 4){
                ushort4 cs = *(const ushort4*)&lst[wave][i];
                const float* q0 = WT + (size_t)cs.x*C_;
                const float* q1 = WT + (size_t)cs.y*C_;
                const float* q2 = WT + (size_t)cs.z*C_;
                const float* q3 = WT + (size_t)cs.w*C_;
#pragma unroll
                for (int j=0;j<6;j++){
                    ya[j] += q0[j<<6]; yb[j] += q1[j<<6];
                    yc[j] += q2[j<<6]; yd[j] += q3[j<<6];
                }
            }
            for (; i < cnt; ++i){
                int c = lst[wave][i];
                const float* q0 = WT + (size_t)c*C_;
#pragma unroll
                for (int j=0;j<6;j++) ya[j] += q0[j<<6];
            }
            float* vs = (br==0)?v0:(br==1)?v1:v2;
            uint32_t words[12];
#pragma unroll
            for (int j=0;j<6;j++){
                int o = (j<<6) + lane;
                float val = ((ya[j]+yb[j])+(yc[j]+yd[j]))*scLDS[br*C_+o] + shLDS[br*C_+o];
                float vv = vs[j];
                vv = vv + (val - vv)*0.5f;
                int s = (vv >= 1.0f);
                unsigned long long bal = __ballot(s);
                if (s) vv = 0.f;
                vs[j] = vv;
                words[2*j]   = (uint32_t)bal;
                words[2*j+1] = (uint32_t)(bal>>32);
            }
            if (lane == 0){
                uint32_t* mo = (br==0)?moQ:(br==1)?moK:moV;
                uint4* o4 = (uint4*)(mo + pix*NW);
                o4[0] = make_uint4(words[0],words[1],words[2],words[3]);
                o4[1] = make_uint4(words[4],words[5],words[6],words[7]);
                o4[2] = make_uint4(words[8],words[9],words[10],words[11]);
            }
        }
        __syncthreads();     // lst reused next t
    }
}

// ---------------------------------------------------------------------------
// K6: spiking attention + attn_lif via C = K^T V (exact integers).
__global__ __launch_bounds__(256) void attention_lif(const uint32_t* __restrict__ mq,
                                                     const uint32_t* __restrict__ mk,
                                                     const uint32_t* __restrict__ mv,
                                                     uint16_t* __restrict__ mo){
    __shared__ unsigned long long kT[DH][4];
    __shared__ unsigned long long vT[DH][4];
    __shared__ uint32_t Cp[DH*25];           // u16-pair packed C, row stride 25

    int h = blockIdx.x & 7;
    int b = blockIdx.x >> 3;
    int tid = threadIdx.x, wv = tid>>6, lane = tid&63;
    int sw  = (h*DH) >> 5;
    int shf = (h*DH) & 31;                   // 0 or 16

    float vm[DH];
#pragma unroll
    for (int d=0;d<DH;d++) vm[d] = 0.f;

    for (int t=0;t<T_;t++){
        int tb = t*B_ + b;
        unsigned long long q = 0, kk = 0, vvv = 0;
        if (tid < N_){
            const uint32_t* pq = mq + ((size_t)tb*N_ + tid)*NW + sw;
            const uint32_t* pk = mk + ((size_t)tb*N_ + tid)*NW + sw;
            const uint32_t* pv = mv + ((size_t)tb*N_ + tid)*NW + sw;
            unsigned long long lo, hi;
            lo = pq[0]; hi = pq[1];
            q   = (shf ? ((lo>>16) | (hi<<16)) : (lo | (hi<<32))) & 0xFFFFFFFFFFFFULL;
            lo = pk[0]; hi = pk[1];
            kk  = (shf ? ((lo>>16) | (hi<<16)) : (lo | (hi<<32))) & 0xFFFFFFFFFFFFULL;
            lo = pv[0]; hi = pv[1];
            vvv = (shf ? ((lo>>16) | (hi<<16)) : (lo | (hi<<32))) & 0xFFFFFFFFFFFFULL;
        }
#pragma unroll 1
        for (int d=0; d<DH; d++){
            unsigned long long bk_ = __ballot((int)((kk >>d)&1ull));
            unsigned long long bv_ = __ballot((int)((vvv>>d)&1ull));
            if (lane == 0){ kT[d][wv] = bk_; vT[d][wv] = bv_; }
        }
        __syncthreads();

        if (tid < 240){
            int j  = tid / 5;
            int dg = tid % 5;
            int d0 = dg*10;
            int d1 = (dg==4) ? 48 : d0+10;
            unsigned long long ka=kT[j][0], kb=kT[j][1], kc=kT[j][2], kd=kT[j][3];
            for (int d=d0; d<d1; d+=2){
                uint32_t c0 = (uint32_t)(__popcll(ka&vT[d][0]) + __popcll(kb&vT[d][1])
                            + __popcll(kc&vT[d][2]) + __popcll(kd&vT[d][3]));
                uint32_t c1 = (uint32_t)(__popcll(ka&vT[d+1][0]) + __popcll(kb&vT[d+1][1])
                            + __popcll(kc&vT[d+1][2]) + __popcll(kd&vT[d+1][3]));
                Cp[j*25 + (d>>1)] = c0 | (c1<<16);
            }
        }
        __syncthreads();

        if (tid < N_){
            uint32_t acc[24];
#pragma unroll
            for (int p=0;p<24;p++) acc[p] = 0u;
            unsigned long long qb = q;
            while (qb){
                int j = __builtin_ctzll(qb); qb &= qb-1;
                const uint32_t* row = &Cp[j*25];
#pragma unroll
                for (int p=0;p<24;p++) acc[p] += row[p];
            }
            unsigned long long sp = 0;
#pragma unroll
            for (int d=0; d<DH; d++){
                uint32_t a = (d&1) ? (acc[d>>1]>>16) : (acc[d>>1]&0xFFFFu);
                float o = 0.125f*(float)a;
                vm[d] = vm[d] + (o - vm[d])*0.5f;
                if (vm[d] >= 0.5f){ sp |= (1ull<<d); vm[d] = 0.f; }
            }
            size_t rec = ((size_t)tb*N_ + tid)*24 + 3*h;   // u16 index
            mo[rec]   = (uint16_t)(sp);
            mo[rec+1] = (uint16_t)(sp >> 16);
            mo[rec+2] = (uint16_t)(sp >> 32);
        }
        __syncthreads();
    }
}

// ---------------------------------------------------------------------------
// K7: proj conv + BN normalize + transposed write via LDS tile.
// Block = (tb, n-quarter, c-half): 49 pixels x 192 channels. 38 KB LDS ->
// 3 blocks/CU; per-wave serial pixel count halved vs round 7.
__global__ __launch_bounds__(256) void proj_out(const uint32_t* __restrict__ mask,
                                                const float* __restrict__ WT,
                                                const float* __restrict__ scale,
                                                const float* __restrict__ shift,
                                                float* __restrict__ out){
    __shared__ float tile[192][49];
    __shared__ uint16_t lst[4][392];
    int bid = blockIdx.x;
    int tb = bid>>3, r7 = bid&7, nq = r7>>1, ch = r7&1;
    int n0 = nq*49, c0 = ch*192;
    int tid = threadIdx.x, wave = tid>>6, lane = tid&63;
    float sc[3], sh[3];
#pragma unroll
    for (int i=0;i<3;i++){
        sc[i] = scale[c0+(i<<6)+lane];
        sh[i] = shift[c0+(i<<6)+lane];
    }
    for (int p=wave; p<49; p+=4){
        size_t pix = (size_t)tb*N_ + n0 + p;
        const uint4* m4 = (const uint4*)(mask + pix*NW);
        uint4 ma = m4[0], mb = m4[1], mc = m4[2];
        uint32_t mwv[12] = {ma.x,ma.y,ma.z,ma.w, mb.x,mb.y,mb.z,mb.w, mc.x,mc.y,mc.z,mc.w};
        int cnt = 0;
#pragma unroll
        for (int w=0;w<12;w++) cnt += __popc(mwv[w]);
        // cooperative list build (lanes 0-11), wave-internal LDS ordering
        if (lane < 12){
            int off = 0;
            uint32_t mybits = 0;
#pragma unroll
            for (int w=0;w<12;w++){
                if (w < lane) off += __popc(mwv[w]);
                if (w == lane) mybits = mwv[w];
            }
            while (mybits){
                lst[wave][off++] = (uint16_t)((lane<<5) + __builtin_ctz(mybits));
                mybits &= mybits - 1;
            }
        }
        float ya[3]={0,0,0}, yb[3]={0,0,0}, yc[3]={0,0,0}, yd[3]={0,0,0};
        int i = 0;
        for (; i+3 < cnt; i += 4){
            ushort4 cs = *(const ushort4*)&lst[wave][i];
            const float* q0 = WT + (size_t)cs.x*C_ + c0 + lane;
            const float* q1 = WT + (size_t)cs.y*C_ + c0 + lane;
            const float* q2 = WT + (size_t)cs.z*C_ + c0 + lane;
            const float* q3 = WT + (size_t)cs.w*C_ + c0 + lane;
#pragma unroll
            for (int j=0;j<3;j++){
                ya[j] += q0[j<<6]; yb[j] += q1[j<<6];
                yc[j] += q2[j<<6]; yd[j] += q3[j<<6];
            }
        }
        for (; i < cnt; ++i){
            int c = lst[wave][i];
            const float* q0 = WT + (size_t)c*C_ + c0 + lane;
#pragma unroll
            for (int j=0;j<3;j++) ya[j] += q0[j<<6];
        }
#pragma unroll
        for (int j=0;j<3;j++)
            tile[(j<<6)+lane][p] = ((ya[j]+yb[j])+(yc[j]+yd[j]))*sc[j] + sh[j];
    }
    __syncthreads();
    for (int r=wave; r<192; r+=4){
        if (lane < 49)
            out[((size_t)tb*C_ + c0 + r)*N_ + n0 + lane] = tile[r][lane];
    }
}

// ---------------------------------------------------------------------------
extern "C" void kernel_launch(void* const* d_in, const int* in_sizes, int n_in,
                              void* d_out, int out_size, void* d_ws, size_t ws_size,
                              hipStream_t stream) {
    const float* x  = (const float*)d_in[0];
    const float* Wq = (const float*)d_in[1];
    const float* Wk = (const float*)d_in[2];
    const float* Wv = (const float*)d_in[3];
    const float* Wp = (const float*)d_in[4];
    const float* gq = (const float*)d_in[5];
    const float* bq = (const float*)d_in[6];
    const float* gk = (const float*)d_in[7];
    const float* bk = (const float*)d_in[8];
    const float* gv = (const float*)d_in[9];
    const float* bv = (const float*)d_in[10];
    const float* gp = (const float*)d_in[11];
    const float* bp = (const float*)d_in[12];

    // workspace carve (~15 MB)
    char* w = (char*)d_ws;
    size_t off = 0;
    uint32_t* maskXS = (uint32_t*)(w + off); off += (size_t)R_*NW*4;   // 2.41 MB each
    uint32_t* maskQ  = (uint32_t*)(w + off); off += (size_t)R_*NW*4;
    uint32_t* maskK  = (uint32_t*)(w + off); off += (size_t)R_*NW*4;
    uint32_t* maskV  = (uint32_t*)(w + off); off += (size_t)R_*NW*4;
    float* WTall = (float*)(w + off); off += (size_t)4*C_*C_*4;        // 2.36 MB
    unsigned long long* maskT = (unsigned long long*)(w + off); off += (size_t)NCH*C_*12*8; // 2.43 MB
    unsigned int* Gu = (unsigned int*)(w + off); off += (size_t)C_*C_*4;  // 0.59 MB
    float* scaleB = (float*)(w + off); off += (size_t)4*C_*4;
    float* shiftB = (float*)(w + off); off += (size_t)4*C_*4;
    uint32_t* maskOL = maskXS;      // alias: XS dead after conv_lif3

    transpose_w4<<<dim3((C_*C_+255)/256, 4),256,0,stream>>>(Wq, Wk, Wv, Wp, WTall);

    pre_lif<<<B_*NW,256,0,stream>>>(x, maskXS);

    // stats for q,k,v branches via one shared Gram of maskXS
    hipMemsetAsync(Gu, 0, (size_t)C_*C_*4, stream);
    bit_transpose<<<198,256,0,stream>>>(maskXS, maskT);
    gram<<<dim3(KG_,6,8),256,0,stream>>>(maskT, Gu);
    bn_from_gram<<<dim3(96,3),384,0,stream>>>(Gu, WTall, gq,bq, gk,bk, gv,bv,
                                              scaleB, shiftB, 0);

    conv_lif3<<<P_/4,256,0,stream>>>(maskXS, WTall, scaleB, shiftB,
                                     maskQ, maskK, maskV);

    attention_lif<<<B_*NH,256,0,stream>>>(maskQ, maskK, maskV, (uint16_t*)maskOL);

    // proj stats via Gram of maskOL
    hipMemsetAsync(Gu, 0, (size_t)C_*C_*4, stream);
    bit_transpose<<<198,256,0,stream>>>(maskOL, maskT);
    gram<<<dim3(KG_,6,8),256,0,stream>>>(maskT, Gu);
    bn_from_gram<<<dim3(96,1),384,0,stream>>>(Gu, WTall, gp,bp, gp,bp, gp,bp,
                                              scaleB + 3*C_, shiftB + 3*C_, 3);

    proj_out<<<TB_*8,256,0,stream>>>(maskOL, WTall + (size_t)3*C_*C_,
                                     scaleB + 3*C_, shiftB + 3*C_, (float*)d_out);
}

// Round 9
// 377.363 us; speedup vs baseline: 1.4709x; 1.0678x over previous
//
#include <hip/hip_runtime.h>
#include <hip/hip_bf16.h>
#include <stdint.h>

// Shapes (hard-coded for this problem)
#define T_  4
#define B_  64
#define C_  384
#define N_  196        // H*W = 14*14
#define NH  8
#define DH  48
#define TB_ (T_*B_)          // 256
#define R_  (T_*B_*N_)       // 50176 pixels total
#define NW  12               // 384 bits -> 12 u32 words per pixel
#define P_  12544            // B_*N_ pixels per timestep
#define NCHX 86              // XS chunks: 1024 groups (tb*4+wave), padded
#define NCHO 66              // OL chunks: 784 groups (t*196+pg), exact+8 pad words

typedef float f32x2 __attribute__((ext_vector_type(2)));

// ---------------------------------------------------------------------------
// K0: LDS-tiled transpose of all 4 weights W[o][c] -> WT[m][c][o]
__global__ __launch_bounds__(256) void transpose_w4(const float* __restrict__ s0,
        const float* __restrict__ s1, const float* __restrict__ s2,
        const float* __restrict__ s3, float* __restrict__ dst){
    __shared__ float tile[64][65];
    int m = blockIdx.z;
    const float* src = (m==0)?s0:(m==1)?s1:(m==2)?s2:s3;
    int o0 = blockIdx.x*64, c0 = blockIdx.y*64;
    int lane = threadIdx.x & 63, w = threadIdx.x >> 6;
    for (int r = w; r < 64; r += 4)
        tile[r][lane] = src[(size_t)(o0+r)*C_ + c0 + lane];
    __syncthreads();
    for (int r = w; r < 64; r += 4)
        dst[(size_t)m*C_*C_ + (size_t)(c0+r)*C_ + o0 + lane] = tile[lane][r];
}

// ---------------------------------------------------------------------------
// K1: pre-LIF on raw x -> spike bitmask + fused bit-transpose into maskT_XS.
// Groups g = tb*4 + wave (1024 groups, wave 3 has 4 lanes -> zero-padded).
__global__ __launch_bounds__(256) void pre_lif(const float* __restrict__ x,
                                               uint32_t* __restrict__ maskXS,
                                               unsigned long long* __restrict__ maskT){
    int b = blockIdx.x / NW;
    int w = blockIdx.x % NW;
    int n = threadIdx.x;
    if (n >= N_) return;
    int wv = n >> 6, lane = n & 63;
    float v[32];
#pragma unroll
    for (int j=0;j<32;j++) v[j] = 0.f;
#pragma unroll
    for (int t=0;t<T_;t++){
        int tb = t*B_ + b;
        uint32_t word = 0;
#pragma unroll
        for (int j=0;j<32;j++){
            int c = w*32 + j;
            float xv = x[((size_t)tb*C_ + c)*N_ + n];
            v[j] = v[j] + (xv - v[j])*0.5f;
            if (v[j] >= 1.0f){ word |= (1u<<j); v[j] = 0.f; }
        }
        maskXS[((size_t)tb*N_ + n)*NW + w] = word;
        int g = tb*4 + wv, kc = g/12, kw = g - kc*12;
#pragma unroll
        for (int j=0;j<32;j++){
            unsigned long long bal = __ballot((int)((word>>j)&1u));
            if (lane == 0)
                maskT[((size_t)kc*C_ + (w*32+j))*12 + kw] = bal;
        }
    }
}

// ---------------------------------------------------------------------------
// K3: Gram: G[c][c'] popcount co-occurrence into global u32 Gu (exact).
// grid (ceil(nch/4), 6 rg, 8 cg); wave handles chunk kc = kg*4+wave.
__global__ __launch_bounds__(256) void gram(const unsigned long long* __restrict__ maskT,
                                            unsigned int* __restrict__ Gu, int nch){
    __shared__ unsigned int tile[64][49];
    int tid = threadIdx.x, wave = tid>>6, lane = tid&63;
    int kg = blockIdx.x, rg = blockIdx.y, cg = blockIdx.z;
    for (int i=tid; i<64*49; i+=256) ((unsigned int*)tile)[i] = 0u;
    __syncthreads();
    int kc = kg*4 + wave;
    if (kc < nch){
        const uint4* rp = (const uint4*)(maskT + ((size_t)kc*C_ + rg*64 + lane)*12);
        uint32_t row[24];
#pragma unroll
        for (int q=0;q<6;q++){
            uint4 a = rp[q];
            row[4*q]=a.x; row[4*q+1]=a.y; row[4*q+2]=a.z; row[4*q+3]=a.w;
        }
        for (int cc=0; cc<48; cc++){
            const uint4* cp = (const uint4*)(maskT + ((size_t)kc*C_ + cg*48 + cc)*12);
            uint32_t col[24];
#pragma unroll
            for (int q=0;q<6;q++){
                uint4 a = cp[q];
                col[4*q]=a.x; col[4*q+1]=a.y; col[4*q+2]=a.z; col[4*q+3]=a.w;
            }
            unsigned int s = 0;
#pragma unroll
            for (int q=0;q<24;q++) s += (unsigned int)__popc(row[q]&col[q]);
            atomicAdd(&tile[lane][cc], s);
        }
    }
    __syncthreads();
    for (int i=tid; i<64*48; i+=256){
        int r = i/48, cc = i%48;
        unsigned int v = tile[r][cc];
        if (v) atomicAdd(&Gu[(size_t)(rg*64+r)*C_ + cg*48 + cc], v);
    }
}

// ---------------------------------------------------------------------------
// K4: BN scale/shift from Gram: sum[o]=sum_c cnt[c] w[c], sumsq[o]=w^T G w.
__global__ __launch_bounds__(384) void bn_from_gram(const unsigned int* __restrict__ Gu,
        const float* __restrict__ WTall,
        const float* __restrict__ g0, const float* __restrict__ b0,
        const float* __restrict__ g1, const float* __restrict__ b1,
        const float* __restrict__ g2, const float* __restrict__ b2,
        float* __restrict__ scaleOut, float* __restrict__ shiftOut, int wtBase){
    __shared__ float w4[384][4];
    __shared__ float sred[8][6];
    int t = threadIdx.x, wave = t>>6, lane = t&63;
    int br = blockIdx.y;
    const float* WT = WTall + (size_t)(wtBase+br)*C_*C_;
    int o0 = blockIdx.x*4;
    float4 wv = *(const float4*)(WT + (size_t)t*C_ + o0);
    w4[t][0]=wv.x; w4[t][1]=wv.y; w4[t][2]=wv.z; w4[t][3]=wv.w;
    __syncthreads();
    float h0=0.f,h1=0.f,h2=0.f,h3=0.f;
#pragma unroll 4
    for (int c=0;c<C_;c++){
        float gv = (float)Gu[(size_t)c*C_ + t];
        float4 wc = *(const float4*)&w4[c][0];
        h0 += gv*wc.x; h1 += gv*wc.y; h2 += gv*wc.z; h3 += gv*wc.w;
    }
    float cnt = (float)Gu[(size_t)t*C_ + t];
    float p0=wv.x*h0, p1=wv.y*h1, p2=wv.z*h2, p3=wv.w*h3;
    float q0=cnt*wv.x, q1=cnt*wv.y, q2=cnt*wv.z, q3=cnt*wv.w;
#pragma unroll
    for (int off=32; off>0; off>>=1){
        p0+=__shfl_down(p0,off); p1+=__shfl_down(p1,off);
        p2+=__shfl_down(p2,off); p3+=__shfl_down(p3,off);
        q0+=__shfl_down(q0,off); q1+=__shfl_down(q1,off);
        q2+=__shfl_down(q2,off); q3+=__shfl_down(q3,off);
    }
    if (lane == 0){
        sred[0][wave]=p0; sred[1][wave]=p1; sred[2][wave]=p2; sred[3][wave]=p3;
        sred[4][wave]=q0; sred[5][wave]=q1; sred[6][wave]=q2; sred[7][wave]=q3;
    }
    __syncthreads();
    if (t < 4){
        const float* g  = (br==0)?g0:(br==1)?g1:g2;
        const float* bb = (br==0)?b0:(br==1)?b1:b2;
        float ss = ((sred[t][0]+sred[t][1])+(sred[t][2]+sred[t][3]))+(sred[t][4]+sred[t][5]);
        float sm = ((sred[4+t][0]+sred[4+t][1])+(sred[4+t][2]+sred[4+t][3]))+(sred[4+t][4]+sred[4+t][5]);
        float m   = sm / (float)R_;
        float var = ss / (float)R_ - m*m;
        float sc  = g[o0+t] / sqrtf(var + 1e-5f);
        scaleOut[br*C_ + o0+t] = sc;
        shiftOut[br*C_ + o0+t] = bb[o0+t] - m*sc;
    }
}

// ---------------------------------------------------------------------------
// K5: sparse conv + fused BN + LIF + pack, ALL 3 branches per wave.
// (L2-BW bound at ~35 TB/s — at the roofline for exact f32 gather.)
__global__ __launch_bounds__(256) void conv_lif3(const uint32_t* __restrict__ mask,
        const float* __restrict__ WTall,
        const float* __restrict__ scaleAll, const float* __restrict__ shiftAll,
        uint32_t* __restrict__ moQ, uint32_t* __restrict__ moK, uint32_t* __restrict__ moV){
    __shared__ uint16_t lst[4][416];
    __shared__ float scLDS[3*C_];
    __shared__ float shLDS[3*C_];
    int tid = threadIdx.x, wave = tid>>6, lane = tid&63;
    int pix0 = blockIdx.x*4 + wave;
    for (int i=tid; i<3*C_; i+=256){ scLDS[i]=scaleAll[i]; shLDS[i]=shiftAll[i]; }
    __syncthreads();

    float v0[6]={0,0,0,0,0,0}, v1[6]={0,0,0,0,0,0}, v2[6]={0,0,0,0,0,0};
    for (int t=0;t<T_;t++){
        size_t pix = (size_t)t*P_ + pix0;
        const uint4* m4 = (const uint4*)(mask + pix*NW);
        uint4 ma = m4[0], mb = m4[1], mc = m4[2];       // wave-uniform
        uint32_t mwv[12] = {ma.x,ma.y,ma.z,ma.w, mb.x,mb.y,mb.z,mb.w, mc.x,mc.y,mc.z,mc.w};
        int cnt = 0;
#pragma unroll
        for (int w=0;w<12;w++) cnt += __popc(mwv[w]);
        if (lane < 12){
            int off = 0;
            uint32_t mybits = 0;
#pragma unroll
            for (int w=0;w<12;w++){
                if (w < lane) off += __popc(mwv[w]);
                if (w == lane) mybits = mwv[w];
            }
            while (mybits){
                lst[wave][off++] = (uint16_t)((lane<<5) + __builtin_ctz(mybits));
                mybits &= mybits - 1;
            }
        }
        __syncthreads();

#pragma unroll
        for (int br=0; br<3; ++br){
            const float* WT = WTall + (size_t)br*C_*C_ + lane;
            float ya[6]={0,0,0,0,0,0}, yb[6]={0,0,0,0,0,0};
            float yc[6]={0,0,0,0,0,0}, yd[6]={0,0,0,0,0,0};
            int i = 0;
            for (; i+3 < cnt; i += 4){
                ushort4 cs = *(const ushort4*)&lst[wave][i];
                const float* q0 = WT + (size_t)cs.x*C_;
                const float* q1 = WT + (size_t)cs.y*C_;
                const float* q2 = WT + (size_t)cs.z*C_;
                const float* q3 = WT + (size_t)cs.w*C_;
#pragma unroll
                for (int j=0;j<6;j++){
                    ya[j] += q0[j<<6]; yb[j] += q1[j<<6];
                    yc[j] += q2[j<<6]; yd[j] += q3[j<<6];
                }
            }
            for (; i < cnt; ++i){
                int c = lst[wave][i];
                const float* q0 = WT + (size_t)c*C_;
#pragma unroll
                for (int j=0;j<6;j++) ya[j] += q0[j<<6];
            }
            float* vs = (br==0)?v0:(br==1)?v1:v2;
            uint32_t words[12];
#pragma unroll
            for (int j=0;j<6;j++){
                int o = (j<<6) + lane;
                float val = ((ya[j]+yb[j])+(yc[j]+yd[j]))*scLDS[br*C_+o] + shLDS[br*C_+o];
                float vv = vs[j];
                vv = vv + (val - vv)*0.5f;
                int s = (vv >= 1.0f);
                unsigned long long bal = __ballot(s);
                if (s) vv = 0.f;
                vs[j] = vv;
                words[2*j]   = (uint32_t)bal;
                words[2*j+1] = (uint32_t)(bal>>32);
            }
            if (lane == 0){
                uint32_t* mo = (br==0)?moQ:(br==1)?moK:moV;
                uint4* o4 = (uint4*)(mo + pix*NW);
                o4[0] = make_uint4(words[0],words[1],words[2],words[3]);
                o4[1] = make_uint4(words[4],words[5],words[6],words[7]);
                o4[2] = make_uint4(words[8],words[9],words[10],words[11]);
            }
        }
        __syncthreads();     // lst reused next t
    }
}

// ---------------------------------------------------------------------------
// K6a: attention counts via C = K^T V (exact integers), one block per (tb,h).
// Writes a[(tb*8+h)][n][24 u32] = 48 packed u16 counts per token.
__global__ __launch_bounds__(256) void attn_O(const uint32_t* __restrict__ mq,
                                              const uint32_t* __restrict__ mk,
                                              const uint32_t* __restrict__ mv,
                                              uint32_t* __restrict__ aCnt){
    __shared__ unsigned long long kT[DH][4];
    __shared__ unsigned long long vT[DH][4];
    __shared__ uint32_t Cp[DH*25];           // u16-pair packed C, row stride 25

    int h  = blockIdx.x & 7;
    int tb = blockIdx.x >> 3;
    int tid = threadIdx.x, wv = tid>>6, lane = tid&63;
    int sw  = (h*DH) >> 5;
    int shf = (h*DH) & 31;                   // 0 or 16

    unsigned long long q = 0, kk = 0, vvv = 0;
    if (tid < N_){
        const uint32_t* pq = mq + ((size_t)tb*N_ + tid)*NW + sw;
        const uint32_t* pk = mk + ((size_t)tb*N_ + tid)*NW + sw;
        const uint32_t* pv = mv + ((size_t)tb*N_ + tid)*NW + sw;
        unsigned long long lo, hi;
        lo = pq[0]; hi = pq[1];
        q   = (shf ? ((lo>>16) | (hi<<16)) : (lo | (hi<<32))) & 0xFFFFFFFFFFFFULL;
        lo = pk[0]; hi = pk[1];
        kk  = (shf ? ((lo>>16) | (hi<<16)) : (lo | (hi<<32))) & 0xFFFFFFFFFFFFULL;
        lo = pv[0]; hi = pv[1];
        vvv = (shf ? ((lo>>16) | (hi<<16)) : (lo | (hi<<32))) & 0xFFFFFFFFFFFFULL;
    }
#pragma unroll 1
    for (int d=0; d<DH; d++){
        unsigned long long bk_ = __ballot((int)((kk >>d)&1ull));
        unsigned long long bv_ = __ballot((int)((vvv>>d)&1ull));
        if (lane == 0){ kT[d][wv] = bk_; vT[d][wv] = bv_; }
    }
    __syncthreads();

    if (tid < 240){
        int j  = tid / 5;
        int dg = tid % 5;
        int d0 = dg*10;
        int d1 = (dg==4) ? 48 : d0+10;
        unsigned long long ka=kT[j][0], kb=kT[j][1], kc=kT[j][2], kd=kT[j][3];
        for (int d=d0; d<d1; d+=2){
            uint32_t c0 = (uint32_t)(__popcll(ka&vT[d][0]) + __popcll(kb&vT[d][1])
                        + __popcll(kc&vT[d][2]) + __popcll(kd&vT[d][3]));
            uint32_t c1 = (uint32_t)(__popcll(ka&vT[d+1][0]) + __popcll(kb&vT[d+1][1])
                        + __popcll(kc&vT[d+1][2]) + __popcll(kd&vT[d+1][3]));
            Cp[j*25 + (d>>1)] = c0 | (c1<<16);
        }
    }
    __syncthreads();

    if (tid < N_){
        uint32_t acc[24];
#pragma unroll
        for (int p=0;p<24;p++) acc[p] = 0u;
        unsigned long long qb = q;
        while (qb){
            int j = __builtin_ctzll(qb); qb &= qb-1;
            const uint32_t* row = &Cp[j*25];
#pragma unroll
            for (int p=0;p<24;p++) acc[p] += row[p];
        }
        uint4* ap = (uint4*)(aCnt + (((size_t)tb*NH + h)*N_ + tid)*24);
        ap[0] = make_uint4(acc[0], acc[1], acc[2], acc[3]);
        ap[1] = make_uint4(acc[4], acc[5], acc[6], acc[7]);
        ap[2] = make_uint4(acc[8], acc[9], acc[10],acc[11]);
        ap[3] = make_uint4(acc[12],acc[13],acc[14],acc[15]);
        ap[4] = make_uint4(acc[16],acc[17],acc[18],acc[19]);
        ap[5] = make_uint4(acc[20],acc[21],acc[22],acc[23]);
    }
}

// ---------------------------------------------------------------------------
// K6b: attn LIF over counts (vth=0.5) -> mo u16 spikes + fused bit-transpose
// into maskT_OL. Block = 1 wave: lane = pixel in group pg; c16 = 16-ch slice.
__global__ __launch_bounds__(64) void attn_lif(const uint32_t* __restrict__ aCnt,
                                               uint16_t* __restrict__ mo,
                                               unsigned long long* __restrict__ maskT){
    int pg  = blockIdx.x;                 // 0..195
    int c16 = blockIdx.y;                 // 0..23
    int lane = threadIdx.x;
    int pix0 = pg*64 + lane;              // (b,n) index, 196*64 = 12544 exact
    int b = pix0 / N_;
    int n = pix0 - b*N_;
    int h = c16 / 3, sub = c16 - h*3;
    float vm[16];
#pragma unroll
    for (int cc=0;cc<16;cc++) vm[cc] = 0.f;
#pragma unroll
    for (int t=0;t<T_;t++){
        int tb = t*B_ + b;
        const uint4* ap = (const uint4*)(aCnt + (((size_t)tb*NH + h)*N_ + n)*24 + sub*8);
        uint4 A = ap[0], Bv = ap[1];
        uint32_t cw[8] = {A.x,A.y,A.z,A.w, Bv.x,Bv.y,Bv.z,Bv.w};
        uint32_t bits = 0;
#pragma unroll
        for (int cc=0;cc<16;cc++){
            uint32_t a = (cc&1) ? (cw[cc>>1]>>16) : (cw[cc>>1]&0xFFFFu);
            float o = 0.125f*(float)a;
            vm[cc] = vm[cc] + (o - vm[cc])*0.5f;
            if (vm[cc] >= 0.5f){ bits |= (1u<<cc); vm[cc] = 0.f; }
        }
        mo[((size_t)t*P_ + pix0)*24 + c16] = (uint16_t)bits;
        int g = t*196 + pg, kc = g/12, kw = g - kc*12;
#pragma unroll
        for (int cc=0;cc<16;cc++){
            unsigned long long bal = __ballot((int)((bits>>cc)&1u));
            if (lane == 0)
                maskT[((size_t)kc*C_ + c16*16 + cc)*12 + kw] = bal;
        }
    }
}

// ---------------------------------------------------------------------------
// K7: proj conv + BN normalize + transposed write via LDS tile.
__global__ __launch_bounds__(256) void proj_out(const uint32_t* __restrict__ mask,
                                                const float* __restrict__ WT,
                                                const float* __restrict__ scale,
                                                const float* __restrict__ shift,
                                                float* __restrict__ out){
    __shared__ float tile[192][49];
    __shared__ uint16_t lst[4][392];
    int bid = blockIdx.x;
    int tb = bid>>3, r7 = bid&7, nq = r7>>1, ch = r7&1;
    int n0 = nq*49, c0 = ch*192;
    int tid = threadIdx.x, wave = tid>>6, lane = tid&63;
    float sc[3], sh[3];
#pragma unroll
    for (int i=0;i<3;i++){
        sc[i] = scale[c0+(i<<6)+lane];
        sh[i] = shift[c0+(i<<6)+lane];
    }
    for (int p=wave; p<49; p+=4){
        size_t pix = (size_t)tb*N_ + n0 + p;
        const uint4* m4 = (const uint4*)(mask + pix*NW);
        uint4 ma = m4[0], mb = m4[1], mc = m4[2];
        uint32_t mwv[12] = {ma.x,ma.y,ma.z,ma.w, mb.x,mb.y,mb.z,mb.w, mc.x,mc.y,mc.z,mc.w};
        int cnt = 0;
#pragma unroll
        for (int w=0;w<12;w++) cnt += __popc(mwv[w]);
        if (lane < 12){
            int off = 0;
            uint32_t mybits = 0;
#pragma unroll
            for (int w=0;w<12;w++){
                if (w < lane) off += __popc(mwv[w]);
                if (w == lane) mybits = mwv[w];
            }
            while (mybits){
                lst[wave][off++] = (uint16_t)((lane<<5) + __builtin_ctz(mybits));
                mybits &= mybits - 1;
            }
        }
        float ya[3]={0,0,0}, yb[3]={0,0,0}, yc[3]={0,0,0}, yd[3]={0,0,0};
        int i = 0;
        for (; i+3 < cnt; i += 4){
            ushort4 cs = *(const ushort4*)&lst[wave][i];
            const float* q0 = WT + (size_t)cs.x*C_ + c0 + lane;
            const float* q1 = WT + (size_t)cs.y*C_ + c0 + lane;
            const float* q2 = WT + (size_t)cs.z*C_ + c0 + lane;
            const float* q3 = WT + (size_t)cs.w*C_ + c0 + lane;
#pragma unroll
            for (int j=0;j<3;j++){
                ya[j] += q0[j<<6]; yb[j] += q1[j<<6];
                yc[j] += q2[j<<6]; yd[j] += q3[j<<6];
            }
        }
        for (; i < cnt; ++i){
            int c = lst[wave][i];
            const float* q0 = WT + (size_t)c*C_ + c0 + lane;
#pragma unroll
            for (int j=0;j<3;j++) ya[j] += q0[j<<6];
        }
#pragma unroll
        for (int j=0;j<3;j++)
            tile[(j<<6)+lane][p] = ((ya[j]+yb[j])+(yc[j]+yd[j]))*sc[j] + sh[j];
    }
    __syncthreads();
    for (int r=wave; r<192; r+=4){
        if (lane < 49)
            out[((size_t)tb*C_ + c0 + r)*N_ + n0 + lane] = tile[r][lane];
    }
}

// ---------------------------------------------------------------------------
extern "C" void kernel_launch(void* const* d_in, const int* in_sizes, int n_in,
                              void* d_out, int out_size, void* d_ws, size_t ws_size,
                              hipStream_t stream) {
    const float* x  = (const float*)d_in[0];
    const float* Wq = (const float*)d_in[1];
    const float* Wk = (const float*)d_in[2];
    const float* Wv = (const float*)d_in[3];
    const float* Wp = (const float*)d_in[4];
    const float* gq = (const float*)d_in[5];
    const float* bq = (const float*)d_in[6];
    const float* gk = (const float*)d_in[7];
    const float* bk = (const float*)d_in[8];
    const float* gv = (const float*)d_in[9];
    const float* bv = (const float*)d_in[10];
    const float* gp = (const float*)d_in[11];
    const float* bp = (const float*)d_in[12];

    // workspace carve (~57 MB)
    char* w = (char*)d_ws;
    size_t off = 0;
    uint32_t* maskXS = (uint32_t*)(w + off); off += (size_t)R_*NW*4;   // 2.41 MB each
    uint32_t* maskQ  = (uint32_t*)(w + off); off += (size_t)R_*NW*4;
    uint32_t* maskK  = (uint32_t*)(w + off); off += (size_t)R_*NW*4;
    uint32_t* maskV  = (uint32_t*)(w + off); off += (size_t)R_*NW*4;
    float* WTall = (float*)(w + off); off += (size_t)4*C_*C_*4;        // 2.36 MB
    // zero-init region: [maskT_XS][maskT_OL][GuXS][GuOL] (one memset)
    unsigned long long* maskTX = (unsigned long long*)(w + off); off += (size_t)NCHX*C_*12*8; // 3.17 MB
    unsigned long long* maskTO = (unsigned long long*)(w + off); off += (size_t)NCHO*C_*12*8; // 2.43 MB
    unsigned int* GuX = (unsigned int*)(w + off); off += (size_t)C_*C_*4;  // 0.59 MB
    unsigned int* GuO = (unsigned int*)(w + off); off += (size_t)C_*C_*4;
    size_t zbytes = (size_t)NCHX*C_*12*8 + (size_t)NCHO*C_*12*8 + 2*(size_t)C_*C_*4;
    uint32_t* aCnt = (uint32_t*)(w + off); off += (size_t)R_*NH*24*4;  // 38.5 MB
    float* scaleB = (float*)(w + off); off += (size_t)4*C_*4;
    float* shiftB = (float*)(w + off); off += (size_t)4*C_*4;
    uint32_t* maskOL = maskXS;      // alias: XS dead after conv_lif3

    hipMemsetAsync(maskTX, 0, zbytes, stream);

    transpose_w4<<<dim3(6,6,4),256,0,stream>>>(Wq, Wk, Wv, Wp, WTall);

    pre_lif<<<B_*NW,256,0,stream>>>(x, maskXS, maskTX);

    gram<<<dim3((NCHX+3)/4,6,8),256,0,stream>>>(maskTX, GuX, NCHX);
    bn_from_gram<<<dim3(96,3),384,0,stream>>>(GuX, WTall, gq,bq, gk,bk, gv,bv,
                                              scaleB, shiftB, 0);

    conv_lif3<<<P_/4,256,0,stream>>>(maskXS, WTall, scaleB, shiftB,
                                     maskQ, maskK, maskV);

    attn_O<<<TB_*NH,256,0,stream>>>(maskQ, maskK, maskV, aCnt);
    attn_lif<<<dim3(196,24),64,0,stream>>>(aCnt, (uint16_t*)maskOL, maskTO);

    gram<<<dim3((NCHO+3)/4,6,8),256,0,stream>>>(maskTO, GuO, NCHO);
    bn_from_gram<<<dim3(96,1),384,0,stream>>>(GuO, WTall, gp,bp, gp,bp, gp,bp,
                                              scaleB + 3*C_, shiftB + 3*C_, 3);

    proj_out<<<TB_*8,256,0,stream>>>(maskOL, WTall + (size_t)3*C_*C_,
                                     scaleB + 3*C_, shiftB + 3*C_, (float*)d_out);
}

// Round 10
// 376.478 us; speedup vs baseline: 1.4743x; 1.0024x over previous
//
#include <hip/hip_runtime.h>
#include <hip/hip_bf16.h>
#include <stdint.h>

// Shapes (hard-coded for this problem)
#define T_  4
#define B_  64
#define C_  384
#define N_  196        // H*W = 14*14
#define NH  8
#define DH  48
#define TB_ (T_*B_)          // 256
#define R_  (T_*B_*N_)       // 50176 pixels total
#define NW  12               // 384 bits -> 12 u32 words per pixel
#define P_  12544            // B_*N_ pixels per timestep
#define NCHX 86              // XS chunks: 1024 groups (tb*4+wave), padded
#define NCHO 66              // OL chunks: 784 groups (t*196+pg), exact+8 pad words

typedef float f32x2 __attribute__((ext_vector_type(2)));

// ---------------------------------------------------------------------------
// K0: LDS-tiled transpose of all 4 weights W[o][c] -> WT[m][c][o]
__global__ __launch_bounds__(256) void transpose_w4(const float* __restrict__ s0,
        const float* __restrict__ s1, const float* __restrict__ s2,
        const float* __restrict__ s3, float* __restrict__ dst){
    __shared__ float tile[64][65];
    int m = blockIdx.z;
    const float* src = (m==0)?s0:(m==1)?s1:(m==2)?s2:s3;
    int o0 = blockIdx.x*64, c0 = blockIdx.y*64;
    int lane = threadIdx.x & 63, w = threadIdx.x >> 6;
    for (int r = w; r < 64; r += 4)
        tile[r][lane] = src[(size_t)(o0+r)*C_ + c0 + lane];
    __syncthreads();
    for (int r = w; r < 64; r += 4)
        dst[(size_t)m*C_*C_ + (size_t)(c0+r)*C_ + o0 + lane] = tile[lane][r];
}

// ---------------------------------------------------------------------------
// K1: pre-LIF on raw x -> spike bitmask + fused bit-transpose into maskT_XS.
// Groups g = tb*4 + wave (1024 groups, wave 3 has 4 lanes -> zero-padded).
__global__ __launch_bounds__(256) void pre_lif(const float* __restrict__ x,
                                               uint32_t* __restrict__ maskXS,
                                               unsigned long long* __restrict__ maskT){
    int b = blockIdx.x / NW;
    int w = blockIdx.x % NW;
    int n = threadIdx.x;
    if (n >= N_) return;
    int wv = n >> 6, lane = n & 63;
    float v[32];
#pragma unroll
    for (int j=0;j<32;j++) v[j] = 0.f;
#pragma unroll
    for (int t=0;t<T_;t++){
        int tb = t*B_ + b;
        uint32_t word = 0;
#pragma unroll
        for (int j=0;j<32;j++){
            int c = w*32 + j;
            float xv = x[((size_t)tb*C_ + c)*N_ + n];
            v[j] = v[j] + (xv - v[j])*0.5f;
            if (v[j] >= 1.0f){ word |= (1u<<j); v[j] = 0.f; }
        }
        maskXS[((size_t)tb*N_ + n)*NW + w] = word;
        int g = tb*4 + wv, kc = g/12, kw = g - kc*12;
#pragma unroll
        for (int j=0;j<32;j++){
            unsigned long long bal = __ballot((int)((word>>j)&1u));
            if (lane == 0)
                maskT[((size_t)kc*C_ + (w*32+j))*12 + kw] = bal;
        }
    }
}

// ---------------------------------------------------------------------------
// K3: Gram: G[c][c'] popcount co-occurrence into global u32 Gu (exact).
// grid (ceil(nch/4), 6 rg, 8 cg); wave handles chunk kc = kg*4+wave.
__global__ __launch_bounds__(256) void gram(const unsigned long long* __restrict__ maskT,
                                            unsigned int* __restrict__ Gu, int nch){
    __shared__ unsigned int tile[64][49];
    int tid = threadIdx.x, wave = tid>>6, lane = tid&63;
    int kg = blockIdx.x, rg = blockIdx.y, cg = blockIdx.z;
    for (int i=tid; i<64*49; i+=256) ((unsigned int*)tile)[i] = 0u;
    __syncthreads();
    int kc = kg*4 + wave;
    if (kc < nch){
        const uint4* rp = (const uint4*)(maskT + ((size_t)kc*C_ + rg*64 + lane)*12);
        uint32_t row[24];
#pragma unroll
        for (int q=0;q<6;q++){
            uint4 a = rp[q];
            row[4*q]=a.x; row[4*q+1]=a.y; row[4*q+2]=a.z; row[4*q+3]=a.w;
        }
        for (int cc=0; cc<48; cc++){
            const uint4* cp = (const uint4*)(maskT + ((size_t)kc*C_ + cg*48 + cc)*12);
            uint32_t col[24];
#pragma unroll
            for (int q=0;q<6;q++){
                uint4 a = cp[q];
                col[4*q]=a.x; col[4*q+1]=a.y; col[4*q+2]=a.z; col[4*q+3]=a.w;
            }
            unsigned int s = 0;
#pragma unroll
            for (int q=0;q<24;q++) s += (unsigned int)__popc(row[q]&col[q]);
            atomicAdd(&tile[lane][cc], s);
        }
    }
    __syncthreads();
    for (int i=tid; i<64*48; i+=256){
        int r = i/48, cc = i%48;
        unsigned int v = tile[r][cc];
        if (v) atomicAdd(&Gu[(size_t)(rg*64+r)*C_ + cg*48 + cc], v);
    }
}

// ---------------------------------------------------------------------------
// K4: BN scale/shift from Gram: sum[o]=sum_c cnt[c] w[c], sumsq[o]=w^T G w.
__global__ __launch_bounds__(384) void bn_from_gram(const unsigned int* __restrict__ Gu,
        const float* __restrict__ WTall,
        const float* __restrict__ g0, const float* __restrict__ b0,
        const float* __restrict__ g1, const float* __restrict__ b1,
        const float* __restrict__ g2, const float* __restrict__ b2,
        float* __restrict__ scaleOut, float* __restrict__ shiftOut, int wtBase){
    __shared__ float w4[384][4];
    __shared__ float sred[8][6];
    int t = threadIdx.x, wave = t>>6, lane = t&63;
    int br = blockIdx.y;
    const float* WT = WTall + (size_t)(wtBase+br)*C_*C_;
    int o0 = blockIdx.x*4;
    float4 wv = *(const float4*)(WT + (size_t)t*C_ + o0);
    w4[t][0]=wv.x; w4[t][1]=wv.y; w4[t][2]=wv.z; w4[t][3]=wv.w;
    __syncthreads();
    float h0=0.f,h1=0.f,h2=0.f,h3=0.f;
#pragma unroll 4
    for (int c=0;c<C_;c++){
        float gv = (float)Gu[(size_t)c*C_ + t];
        float4 wc = *(const float4*)&w4[c][0];
        h0 += gv*wc.x; h1 += gv*wc.y; h2 += gv*wc.z; h3 += gv*wc.w;
    }
    float cnt = (float)Gu[(size_t)t*C_ + t];
    float p0=wv.x*h0, p1=wv.y*h1, p2=wv.z*h2, p3=wv.w*h3;
    float q0=cnt*wv.x, q1=cnt*wv.y, q2=cnt*wv.z, q3=cnt*wv.w;
#pragma unroll
    for (int off=32; off>0; off>>=1){
        p0+=__shfl_down(p0,off); p1+=__shfl_down(p1,off);
        p2+=__shfl_down(p2,off); p3+=__shfl_down(p3,off);
        q0+=__shfl_down(q0,off); q1+=__shfl_down(q1,off);
        q2+=__shfl_down(q2,off); q3+=__shfl_down(q3,off);
    }
    if (lane == 0){
        sred[0][wave]=p0; sred[1][wave]=p1; sred[2][wave]=p2; sred[3][wave]=p3;
        sred[4][wave]=q0; sred[5][wave]=q1; sred[6][wave]=q2; sred[7][wave]=q3;
    }
    __syncthreads();
    if (t < 4){
        const float* g  = (br==0)?g0:(br==1)?g1:g2;
        const float* bb = (br==0)?b0:(br==1)?b1:b2;
        float ss = ((sred[t][0]+sred[t][1])+(sred[t][2]+sred[t][3]))+(sred[t][4]+sred[t][5]);
        float sm = ((sred[4+t][0]+sred[4+t][1])+(sred[4+t][2]+sred[4+t][3]))+(sred[4+t][4]+sred[4+t][5]);
        float m   = sm / (float)R_;
        float var = ss / (float)R_ - m*m;
        float sc  = g[o0+t] / sqrtf(var + 1e-5f);
        scaleOut[br*C_ + o0+t] = sc;
        shiftOut[br*C_ + o0+t] = bb[o0+t] - m*sc;
    }
}

// ---------------------------------------------------------------------------
// K5: sparse conv + fused BN + LIF + pack, ALL 3 branches per wave.
// (L2-BW bound at ~35 TB/s — at the roofline for exact f32 gather.)
__global__ __launch_bounds__(256) void conv_lif3(const uint32_t* __restrict__ mask,
        const float* __restrict__ WTall,
        const float* __restrict__ scaleAll, const float* __restrict__ shiftAll,
        uint32_t* __restrict__ moQ, uint32_t* __restrict__ moK, uint32_t* __restrict__ moV){
    __shared__ uint16_t lst[4][416];
    __shared__ float scLDS[3*C_];
    __shared__ float shLDS[3*C_];
    int tid = threadIdx.x, wave = tid>>6, lane = tid&63;
    int pix0 = blockIdx.x*4 + wave;
    for (int i=tid; i<3*C_; i+=256){ scLDS[i]=scaleAll[i]; shLDS[i]=shiftAll[i]; }
    __syncthreads();

    float v0[6]={0,0,0,0,0,0}, v1[6]={0,0,0,0,0,0}, v2[6]={0,0,0,0,0,0};
    for (int t=0;t<T_;t++){
        size_t pix = (size_t)t*P_ + pix0;
        const uint4* m4 = (const uint4*)(mask + pix*NW);
        uint4 ma = m4[0], mb = m4[1], mc = m4[2];       // wave-uniform
        uint32_t mwv[12] = {ma.x,ma.y,ma.z,ma.w, mb.x,mb.y,mb.z,mb.w, mc.x,mc.y,mc.z,mc.w};
        int cnt = 0;
#pragma unroll
        for (int w=0;w<12;w++) cnt += __popc(mwv[w]);
        if (lane < 12){
            int off = 0;
            uint32_t mybits = 0;
#pragma unroll
            for (int w=0;w<12;w++){
                if (w < lane) off += __popc(mwv[w]);
                if (w == lane) mybits = mwv[w];
            }
            while (mybits){
                lst[wave][off++] = (uint16_t)((lane<<5) + __builtin_ctz(mybits));
                mybits &= mybits - 1;
            }
        }
        __syncthreads();

#pragma unroll
        for (int br=0; br<3; ++br){
            const float* WT = WTall + (size_t)br*C_*C_ + lane;
            float ya[6]={0,0,0,0,0,0}, yb[6]={0,0,0,0,0,0};
            float yc[6]={0,0,0,0,0,0}, yd[6]={0,0,0,0,0,0};
            int i = 0;
            for (; i+3 < cnt; i += 4){
                ushort4 cs = *(const ushort4*)&lst[wave][i];
                const float* q0 = WT + (size_t)cs.x*C_;
                const float* q1 = WT + (size_t)cs.y*C_;
                const float* q2 = WT + (size_t)cs.z*C_;
                const float* q3 = WT + (size_t)cs.w*C_;
#pragma unroll
                for (int j=0;j<6;j++){
                    ya[j] += q0[j<<6]; yb[j] += q1[j<<6];
                    yc[j] += q2[j<<6]; yd[j] += q3[j<<6];
                }
            }
            for (; i < cnt; ++i){
                int c = lst[wave][i];
                const float* q0 = WT + (size_t)c*C_;
#pragma unroll
                for (int j=0;j<6;j++) ya[j] += q0[j<<6];
            }
            float* vs = (br==0)?v0:(br==1)?v1:v2;
            uint32_t words[12];
#pragma unroll
            for (int j=0;j<6;j++){
                int o = (j<<6) + lane;
                float val = ((ya[j]+yb[j])+(yc[j]+yd[j]))*scLDS[br*C_+o] + shLDS[br*C_+o];
                float vv = vs[j];
                vv = vv + (val - vv)*0.5f;
                int s = (vv >= 1.0f);
                unsigned long long bal = __ballot(s);
                if (s) vv = 0.f;
                vs[j] = vv;
                words[2*j]   = (uint32_t)bal;
                words[2*j+1] = (uint32_t)(bal>>32);
            }
            if (lane == 0){
                uint32_t* mo = (br==0)?moQ:(br==1)?moK:moV;
                uint4* o4 = (uint4*)(mo + pix*NW);
                o4[0] = make_uint4(words[0],words[1],words[2],words[3]);
                o4[1] = make_uint4(words[4],words[5],words[6],words[7]);
                o4[2] = make_uint4(words[8],words[9],words[10],words[11]);
            }
        }
        __syncthreads();     // lst reused next t
    }
}

// ---------------------------------------------------------------------------
// K6a: attention counts via C = K^T V (exact integers), one block per (tb,h).
// Writes a[(tb*8+h)][n][24 u32] = 48 packed u16 counts per token.
__global__ __launch_bounds__(256) void attn_O(const uint32_t* __restrict__ mq,
                                              const uint32_t* __restrict__ mk,
                                              const uint32_t* __restrict__ mv,
                                              uint32_t* __restrict__ aCnt){
    __shared__ unsigned long long kT[DH][4];
    __shared__ unsigned long long vT[DH][4];
    __shared__ uint32_t Cp[DH*25];           // u16-pair packed C, row stride 25

    int h  = blockIdx.x & 7;
    int tb = blockIdx.x >> 3;
    int tid = threadIdx.x, wv = tid>>6, lane = tid&63;
    int sw  = (h*DH) >> 5;
    int shf = (h*DH) & 31;                   // 0 or 16

    unsigned long long q = 0, kk = 0, vvv = 0;
    if (tid < N_){
        const uint32_t* pq = mq + ((size_t)tb*N_ + tid)*NW + sw;
        const uint32_t* pk = mk + ((size_t)tb*N_ + tid)*NW + sw;
        const uint32_t* pv = mv + ((size_t)tb*N_ + tid)*NW + sw;
        unsigned long long lo, hi;
        lo = pq[0]; hi = pq[1];
        q   = (shf ? ((lo>>16) | (hi<<16)) : (lo | (hi<<32))) & 0xFFFFFFFFFFFFULL;
        lo = pk[0]; hi = pk[1];
        kk  = (shf ? ((lo>>16) | (hi<<16)) : (lo | (hi<<32))) & 0xFFFFFFFFFFFFULL;
        lo = pv[0]; hi = pv[1];
        vvv = (shf ? ((lo>>16) | (hi<<16)) : (lo | (hi<<32))) & 0xFFFFFFFFFFFFULL;
    }
#pragma unroll 1
    for (int d=0; d<DH; d++){
        unsigned long long bk_ = __ballot((int)((kk >>d)&1ull));
        unsigned long long bv_ = __ballot((int)((vvv>>d)&1ull));
        if (lane == 0){ kT[d][wv] = bk_; vT[d][wv] = bv_; }
    }
    __syncthreads();

    if (tid < 240){
        int j  = tid / 5;
        int dg = tid % 5;
        int d0 = dg*10;
        int d1 = (dg==4) ? 48 : d0+10;
        unsigned long long ka=kT[j][0], kb=kT[j][1], kc=kT[j][2], kd=kT[j][3];
        for (int d=d0; d<d1; d+=2){
            uint32_t c0 = (uint32_t)(__popcll(ka&vT[d][0]) + __popcll(kb&vT[d][1])
                        + __popcll(kc&vT[d][2]) + __popcll(kd&vT[d][3]));
            uint32_t c1 = (uint32_t)(__popcll(ka&vT[d+1][0]) + __popcll(kb&vT[d+1][1])
                        + __popcll(kc&vT[d+1][2]) + __popcll(kd&vT[d+1][3]));
            Cp[j*25 + (d>>1)] = c0 | (c1<<16);
        }
    }
    __syncthreads();

    if (tid < N_){
        uint32_t acc[24];
#pragma unroll
        for (int p=0;p<24;p++) acc[p] = 0u;
        unsigned long long qb = q;
        while (qb){
            int j = __builtin_ctzll(qb); qb &= qb-1;
            const uint32_t* row = &Cp[j*25];
#pragma unroll
            for (int p=0;p<24;p++) acc[p] += row[p];
        }
        uint4* ap = (uint4*)(aCnt + (((size_t)tb*NH + h)*N_ + tid)*24);
        ap[0] = make_uint4(acc[0], acc[1], acc[2], acc[3]);
        ap[1] = make_uint4(acc[4], acc[5], acc[6], acc[7]);
        ap[2] = make_uint4(acc[8], acc[9], acc[10],acc[11]);
        ap[3] = make_uint4(acc[12],acc[13],acc[14],acc[15]);
        ap[4] = make_uint4(acc[16],acc[17],acc[18],acc[19]);
        ap[5] = make_uint4(acc[20],acc[21],acc[22],acc[23]);
    }
}

// ---------------------------------------------------------------------------
// K6b: attn LIF over counts (vth=0.5) -> mo u16 spikes + fused bit-transpose
// into maskT_OL. Block = 1 wave: lane = pixel in group pg; c16 = 16-ch slice.
__global__ __launch_bounds__(64) void attn_lif(const uint32_t* __restrict__ aCnt,
                                               uint16_t* __restrict__ mo,
                                               unsigned long long* __restrict__ maskT){
    int pg  = blockIdx.x;                 // 0..195
    int c16 = blockIdx.y;                 // 0..23
    int lane = threadIdx.x;
    int pix0 = pg*64 + lane;              // (b,n) index, 196*64 = 12544 exact
    int b = pix0 / N_;
    int n = pix0 - b*N_;
    int h = c16 / 3, sub = c16 - h*3;
    float vm[16];
#pragma unroll
    for (int cc=0;cc<16;cc++) vm[cc] = 0.f;
#pragma unroll
    for (int t=0;t<T_;t++){
        int tb = t*B_ + b;
        const uint4* ap = (const uint4*)(aCnt + (((size_t)tb*NH + h)*N_ + n)*24 + sub*8);
        uint4 A = ap[0], Bv = ap[1];
        uint32_t cw[8] = {A.x,A.y,A.z,A.w, Bv.x,Bv.y,Bv.z,Bv.w};
        uint32_t bits = 0;
#pragma unroll
        for (int cc=0;cc<16;cc++){
            uint32_t a = (cc&1) ? (cw[cc>>1]>>16) : (cw[cc>>1]&0xFFFFu);
            float o = 0.125f*(float)a;
            vm[cc] = vm[cc] + (o - vm[cc])*0.5f;
            if (vm[cc] >= 0.5f){ bits |= (1u<<cc); vm[cc] = 0.f; }
        }
        mo[((size_t)t*P_ + pix0)*24 + c16] = (uint16_t)bits;
        int g = t*196 + pg, kc = g/12, kw = g - kc*12;
#pragma unroll
        for (int cc=0;cc<16;cc++){
            unsigned long long bal = __ballot((int)((bits>>cc)&1u));
            if (lane == 0)
                maskT[((size_t)kc*C_ + c16*16 + cc)*12 + kw] = bal;
        }
    }
}

// ---------------------------------------------------------------------------
// K7: proj conv + BN normalize + transposed write via LDS tile.
__global__ __launch_bounds__(256) void proj_out(const uint32_t* __restrict__ mask,
                                                const float* __restrict__ WT,
                                                const float* __restrict__ scale,
                                                const float* __restrict__ shift,
                                                float* __restrict__ out){
    __shared__ float tile[192][49];
    __shared__ uint16_t lst[4][392];
    int bid = blockIdx.x;
    int tb = bid>>3, r7 = bid&7, nq = r7>>1, ch = r7&1;
    int n0 = nq*49, c0 = ch*192;
    int tid = threadIdx.x, wave = tid>>6, lane = tid&63;
    float sc[3], sh[3];
#pragma unroll
    for (int i=0;i<3;i++){
        sc[i] = scale[c0+(i<<6)+lane];
        sh[i] = shift[c0+(i<<6)+lane];
    }
    for (int p=wave; p<49; p+=4){
        size_t pix = (size_t)tb*N_ + n0 + p;
        const uint4* m4 = (const uint4*)(mask + pix*NW);
        uint4 ma = m4[0], mb = m4[1], mc = m4[2];
        uint32_t mwv[12] = {ma.x,ma.y,ma.z,ma.w, mb.x,mb.y,mb.z,mb.w, mc.x,mc.y,mc.z,mc.w};
        int cnt = 0;
#pragma unroll
        for (int w=0;w<12;w++) cnt += __popc(mwv[w]);
        if (lane < 12){
            int off = 0;
            uint32_t mybits = 0;
#pragma unroll
            for (int w=0;w<12;w++){
                if (w < lane) off += __popc(mwv[w]);
                if (w == lane) mybits = mwv[w];
            }
            while (mybits){
                lst[wave][off++] = (uint16_t)((lane<<5) + __builtin_ctz(mybits));
                mybits &= mybits - 1;
            }
        }
        float ya[3]={0,0,0}, yb[3]={0,0,0}, yc[3]={0,0,0}, yd[3]={0,0,0};
        int i = 0;
        for (; i+3 < cnt; i += 4){
            ushort4 cs = *(const ushort4*)&lst[wave][i];
            const float* q0 = WT + (size_t)cs.x*C_ + c0 + lane;
            const float* q1 = WT + (size_t)cs.y*C_ + c0 + lane;
            const float* q2 = WT + (size_t)cs.z*C_ + c0 + lane;
            const float* q3 = WT + (size_t)cs.w*C_ + c0 + lane;
#pragma unroll
            for (int j=0;j<3;j++){
                ya[j] += q0[j<<6]; yb[j] += q1[j<<6];
                yc[j] += q2[j<<6]; yd[j] += q3[j<<6];
            }
        }
        for (; i < cnt; ++i){
            int c = lst[wave][i];
            const float* q0 = WT + (size_t)c*C_ + c0 + lane;
#pragma unroll
            for (int j=0;j<3;j++) ya[j] += q0[j<<6];
        }
#pragma unroll
        for (int j=0;j<3;j++)
            tile[(j<<6)+lane][p] = ((ya[j]+yb[j])+(yc[j]+yd[j]))*sc[j] + sh[j];
    }
    __syncthreads();
    for (int r=wave; r<192; r+=4){
        if (lane < 49)
            out[((size_t)tb*C_ + c0 + r)*N_ + n0 + lane] = tile[r][lane];
    }
}

// ---------------------------------------------------------------------------
extern "C" void kernel_launch(void* const* d_in, const int* in_sizes, int n_in,
                              void* d_out, int out_size, void* d_ws, size_t ws_size,
                              hipStream_t stream) {
    const float* x  = (const float*)d_in[0];
    const float* Wq = (const float*)d_in[1];
    const float* Wk = (const float*)d_in[2];
    const float* Wv = (const float*)d_in[3];
    const float* Wp = (const float*)d_in[4];
    const float* gq = (const float*)d_in[5];
    const float* bq = (const float*)d_in[6];
    const float* gk = (const float*)d_in[7];
    const float* bk = (const float*)d_in[8];
    const float* gv = (const float*)d_in[9];
    const float* bv = (const float*)d_in[10];
    const float* gp = (const float*)d_in[11];
    const float* bp = (const float*)d_in[12];

    // workspace carve (~57 MB)
    char* w = (char*)d_ws;
    size_t off = 0;
    uint32_t* maskXS = (uint32_t*)(w + off); off += (size_t)R_*NW*4;   // 2.41 MB each
    uint32_t* maskQ  = (uint32_t*)(w + off); off += (size_t)R_*NW*4;
    uint32_t* maskK  = (uint32_t*)(w + off); off += (size_t)R_*NW*4;
    uint32_t* maskV  = (uint32_t*)(w + off); off += (size_t)R_*NW*4;
    float* WTall = (float*)(w + off); off += (size_t)4*C_*C_*4;        // 2.36 MB
    // zero-init region: [maskT_XS][maskT_OL][GuXS][GuOL] (one memset)
    unsigned long long* maskTX = (unsigned long long*)(w + off); off += (size_t)NCHX*C_*12*8; // 3.17 MB
    unsigned long long* maskTO = (unsigned long long*)(w + off); off += (size_t)NCHO*C_*12*8; // 2.43 MB
    unsigned int* GuX = (unsigned int*)(w + off); off += (size_t)C_*C_*4;  // 0.59 MB
    unsigned int* GuO = (unsigned int*)(w + off); off += (size_t)C_*C_*4;
    size_t zbytes = (size_t)NCHX*C_*12*8 + (size_t)NCHO*C_*12*8 + 2*(size_t)C_*C_*4;
    uint32_t* aCnt = (uint32_t*)(w + off); off += (size_t)R_*NH*24*4;  // 38.5 MB
    float* scaleB = (float*)(w + off); off += (size_t)4*C_*4;
    float* shiftB = (float*)(w + off); off += (size_t)4*C_*4;
    uint32_t* maskOL = maskXS;      // alias: XS dead after conv_lif3

    hipMemsetAsync(maskTX, 0, zbytes, stream);

    transpose_w4<<<dim3(6,6,4),256,0,stream>>>(Wq, Wk, Wv, Wp, WTall);

    pre_lif<<<B_*NW,256,0,stream>>>(x, maskXS, maskTX);

    gram<<<dim3((NCHX+3)/4,6,8),256,0,stream>>>(maskTX, GuX, NCHX);
    bn_from_gram<<<dim3(96,3),384,0,stream>>>(GuX, WTall, gq,bq, gk,bk, gv,bv,
                                              scaleB, shiftB, 0);

    conv_lif3<<<P_/4,256,0,stream>>>(maskXS, WTall, scaleB, shiftB,
                                     maskQ, maskK, maskV);

    attn_O<<<TB_*NH,256,0,stream>>>(maskQ, maskK, maskV, aCnt);
    attn_lif<<<dim3(196,24),64,0,stream>>>(aCnt, (uint16_t*)maskOL, maskTO);

    gram<<<dim3((NCHO+3)/4,6,8),256,0,stream>>>(maskTO, GuO, NCHO);
    bn_from_gram<<<dim3(96,1),384,0,stream>>>(GuO, WTall, gp,bp, gp,bp, gp,bp,
                                              scaleB + 3*C_, shiftB + 3*C_, 3);

    proj_out<<<TB_*8,256,0,stream>>>(maskOL, WTall + (size_t)3*C_*C_,
                                     scaleB + 3*C_, shiftB + 3*C_, (float*)d_out);
}

// Round 11
// 376.322 us; speedup vs baseline: 1.4749x; 1.0004x over previous
//
#include <hip/hip_runtime.h>
#include <hip/hip_bf16.h>
#include <stdint.h>

// Shapes (hard-coded for this problem)
#define T_  4
#define B_  64
#define C_  384
#define N_  196        // H*W = 14*14
#define NH  8
#define DH  48
#define TB_ (T_*B_)          // 256
#define R_  (T_*B_*N_)       // 50176 pixels total
#define NW  12               // 384 bits -> 12 u32 words per pixel
#define P_  12544            // B_*N_ pixels per timestep
#define NCHX 86              // XS chunks: 1024 groups (tb*4+wave), padded
#define NCHO 66              // OL chunks: 784 groups (t*196+pg), exact+8 pad words

typedef float f32x2 __attribute__((ext_vector_type(2)));

// ---------------------------------------------------------------------------
// K0: LDS-tiled transpose of all 4 weights W[o][c] -> WT[m][c][o]
__global__ __launch_bounds__(256) void transpose_w4(const float* __restrict__ s0,
        const float* __restrict__ s1, const float* __restrict__ s2,
        const float* __restrict__ s3, float* __restrict__ dst){
    __shared__ float tile[64][65];
    int m = blockIdx.z;
    const float* src = (m==0)?s0:(m==1)?s1:(m==2)?s2:s3;
    int o0 = blockIdx.x*64, c0 = blockIdx.y*64;
    int lane = threadIdx.x & 63, w = threadIdx.x >> 6;
    for (int r = w; r < 64; r += 4)
        tile[r][lane] = src[(size_t)(o0+r)*C_ + c0 + lane];
    __syncthreads();
    for (int r = w; r < 64; r += 4)
        dst[(size_t)m*C_*C_ + (size_t)(c0+r)*C_ + o0 + lane] = tile[lane][r];
}

// ---------------------------------------------------------------------------
// K1: pre-LIF on raw x -> spike bitmask + fused bit-transpose into maskT_XS.
// Groups g = tb*4 + wave (1024 groups, wave 3 has 4 lanes -> zero-padded).
__global__ __launch_bounds__(256) void pre_lif(const float* __restrict__ x,
                                               uint32_t* __restrict__ maskXS,
                                               unsigned long long* __restrict__ maskT){
    int b = blockIdx.x / NW;
    int w = blockIdx.x % NW;
    int n = threadIdx.x;
    if (n >= N_) return;
    int wv = n >> 6, lane = n & 63;
    float v[32];
#pragma unroll
    for (int j=0;j<32;j++) v[j] = 0.f;
#pragma unroll
    for (int t=0;t<T_;t++){
        int tb = t*B_ + b;
        uint32_t word = 0;
#pragma unroll
        for (int j=0;j<32;j++){
            int c = w*32 + j;
            float xv = x[((size_t)tb*C_ + c)*N_ + n];
            v[j] = v[j] + (xv - v[j])*0.5f;
            if (v[j] >= 1.0f){ word |= (1u<<j); v[j] = 0.f; }
        }
        maskXS[((size_t)tb*N_ + n)*NW + w] = word;
        int g = tb*4 + wv, kc = g/12, kw = g - kc*12;
#pragma unroll
        for (int j=0;j<32;j++){
            unsigned long long bal = __ballot((int)((word>>j)&1u));
            if (lane == 0)
                maskT[((size_t)kc*C_ + (w*32+j))*12 + kw] = bal;
        }
    }
}

// ---------------------------------------------------------------------------
// K3: Gram: G[c][c'] popcount co-occurrence into global u32 Gu (exact).
// grid (ceil(nch/4), 6 rg, 8 cg); wave handles chunk kc = kg*4+wave.
__global__ __launch_bounds__(256) void gram(const unsigned long long* __restrict__ maskT,
                                            unsigned int* __restrict__ Gu, int nch){
    __shared__ unsigned int tile[64][49];
    int tid = threadIdx.x, wave = tid>>6, lane = tid&63;
    int kg = blockIdx.x, rg = blockIdx.y, cg = blockIdx.z;
    for (int i=tid; i<64*49; i+=256) ((unsigned int*)tile)[i] = 0u;
    __syncthreads();
    int kc = kg*4 + wave;
    if (kc < nch){
        const uint4* rp = (const uint4*)(maskT + ((size_t)kc*C_ + rg*64 + lane)*12);
        uint32_t row[24];
#pragma unroll
        for (int q=0;q<6;q++){
            uint4 a = rp[q];
            row[4*q]=a.x; row[4*q+1]=a.y; row[4*q+2]=a.z; row[4*q+3]=a.w;
        }
        for (int cc=0; cc<48; cc++){
            const uint4* cp = (const uint4*)(maskT + ((size_t)kc*C_ + cg*48 + cc)*12);
            uint32_t col[24];
#pragma unroll
            for (int q=0;q<6;q++){
                uint4 a = cp[q];
                col[4*q]=a.x; col[4*q+1]=a.y; col[4*q+2]=a.z; col[4*q+3]=a.w;
            }
            unsigned int s = 0;
#pragma unroll
            for (int q=0;q<24;q++) s += (unsigned int)__popc(row[q]&col[q]);
            atomicAdd(&tile[lane][cc], s);
        }
    }
    __syncthreads();
    for (int i=tid; i<64*48; i+=256){
        int r = i/48, cc = i%48;
        unsigned int v = tile[r][cc];
        if (v) atomicAdd(&Gu[(size_t)(rg*64+r)*C_ + cg*48 + cc], v);
    }
}

// ---------------------------------------------------------------------------
// K4: BN scale/shift from Gram: sum[o]=sum_c cnt[c] w[c], sumsq[o]=w^T G w.
__global__ __launch_bounds__(384) void bn_from_gram(const unsigned int* __restrict__ Gu,
        const float* __restrict__ WTall,
        const float* __restrict__ g0, const float* __restrict__ b0,
        const float* __restrict__ g1, const float* __restrict__ b1,
        const float* __restrict__ g2, const float* __restrict__ b2,
        float* __restrict__ scaleOut, float* __restrict__ shiftOut, int wtBase){
    __shared__ float w4[384][4];
    __shared__ float sred[8][6];
    int t = threadIdx.x, wave = t>>6, lane = t&63;
    int br = blockIdx.y;
    const float* WT = WTall + (size_t)(wtBase+br)*C_*C_;
    int o0 = blockIdx.x*4;
    float4 wv = *(const float4*)(WT + (size_t)t*C_ + o0);
    w4[t][0]=wv.x; w4[t][1]=wv.y; w4[t][2]=wv.z; w4[t][3]=wv.w;
    __syncthreads();
    float h0=0.f,h1=0.f,h2=0.f,h3=0.f;
#pragma unroll 4
    for (int c=0;c<C_;c++){
        float gv = (float)Gu[(size_t)c*C_ + t];
        float4 wc = *(const float4*)&w4[c][0];
        h0 += gv*wc.x; h1 += gv*wc.y; h2 += gv*wc.z; h3 += gv*wc.w;
    }
    float cnt = (float)Gu[(size_t)t*C_ + t];
    float p0=wv.x*h0, p1=wv.y*h1, p2=wv.z*h2, p3=wv.w*h3;
    float q0=cnt*wv.x, q1=cnt*wv.y, q2=cnt*wv.z, q3=cnt*wv.w;
#pragma unroll
    for (int off=32; off>0; off>>=1){
        p0+=__shfl_down(p0,off); p1+=__shfl_down(p1,off);
        p2+=__shfl_down(p2,off); p3+=__shfl_down(p3,off);
        q0+=__shfl_down(q0,off); q1+=__shfl_down(q1,off);
        q2+=__shfl_down(q2,off); q3+=__shfl_down(q3,off);
    }
    if (lane == 0){
        sred[0][wave]=p0; sred[1][wave]=p1; sred[2][wave]=p2; sred[3][wave]=p3;
        sred[4][wave]=q0; sred[5][wave]=q1; sred[6][wave]=q2; sred[7][wave]=q3;
    }
    __syncthreads();
    if (t < 4){
        const float* g  = (br==0)?g0:(br==1)?g1:g2;
        const float* bb = (br==0)?b0:(br==1)?b1:b2;
        float ss = ((sred[t][0]+sred[t][1])+(sred[t][2]+sred[t][3]))+(sred[t][4]+sred[t][5]);
        float sm = ((sred[4+t][0]+sred[4+t][1])+(sred[4+t][2]+sred[4+t][3]))+(sred[4+t][4]+sred[4+t][5]);
        float m   = sm / (float)R_;
        float var = ss / (float)R_ - m*m;
        float sc  = g[o0+t] / sqrtf(var + 1e-5f);
        scaleOut[br*C_ + o0+t] = sc;
        shiftOut[br*C_ + o0+t] = bb[o0+t] - m*sc;
    }
}

// ---------------------------------------------------------------------------
// K5: sparse conv + fused BN + LIF + pack, ALL 3 branches per wave.
// (L2-BW bound at ~35 TB/s — at the roofline for exact f32 gather.)
__global__ __launch_bounds__(256) void conv_lif3(const uint32_t* __restrict__ mask,
        const float* __restrict__ WTall,
        const float* __restrict__ scaleAll, const float* __restrict__ shiftAll,
        uint32_t* __restrict__ moQ, uint32_t* __restrict__ moK, uint32_t* __restrict__ moV){
    __shared__ uint16_t lst[4][416];
    __shared__ float scLDS[3*C_];
    __shared__ float shLDS[3*C_];
    int tid = threadIdx.x, wave = tid>>6, lane = tid&63;
    int pix0 = blockIdx.x*4 + wave;
    for (int i=tid; i<3*C_; i+=256){ scLDS[i]=scaleAll[i]; shLDS[i]=shiftAll[i]; }
    __syncthreads();

    float v0[6]={0,0,0,0,0,0}, v1[6]={0,0,0,0,0,0}, v2[6]={0,0,0,0,0,0};
    for (int t=0;t<T_;t++){
        size_t pix = (size_t)t*P_ + pix0;
        const uint4* m4 = (const uint4*)(mask + pix*NW);
        uint4 ma = m4[0], mb = m4[1], mc = m4[2];       // wave-uniform
        uint32_t mwv[12] = {ma.x,ma.y,ma.z,ma.w, mb.x,mb.y,mb.z,mb.w, mc.x,mc.y,mc.z,mc.w};
        int cnt = 0;
#pragma unroll
        for (int w=0;w<12;w++) cnt += __popc(mwv[w]);
        if (lane < 12){
            int off = 0;
            uint32_t mybits = 0;
#pragma unroll
            for (int w=0;w<12;w++){
                if (w < lane) off += __popc(mwv[w]);
                if (w == lane) mybits = mwv[w];
            }
            while (mybits){
                lst[wave][off++] = (uint16_t)((lane<<5) + __builtin_ctz(mybits));
                mybits &= mybits - 1;
            }
        }
        __syncthreads();

#pragma unroll
        for (int br=0; br<3; ++br){
            const float* WT = WTall + (size_t)br*C_*C_ + lane;
            float ya[6]={0,0,0,0,0,0}, yb[6]={0,0,0,0,0,0};
            float yc[6]={0,0,0,0,0,0}, yd[6]={0,0,0,0,0,0};
            int i = 0;
            for (; i+3 < cnt; i += 4){
                ushort4 cs = *(const ushort4*)&lst[wave][i];
                const float* q0 = WT + (size_t)cs.x*C_;
                const float* q1 = WT + (size_t)cs.y*C_;
                const float* q2 = WT + (size_t)cs.z*C_;
                const float* q3 = WT + (size_t)cs.w*C_;
#pragma unroll
                for (int j=0;j<6;j++){
                    ya[j] += q0[j<<6]; yb[j] += q1[j<<6];
                    yc[j] += q2[j<<6]; yd[j] += q3[j<<6];
                }
            }
            for (; i < cnt; ++i){
                int c = lst[wave][i];
                const float* q0 = WT + (size_t)c*C_;
#pragma unroll
                for (int j=0;j<6;j++) ya[j] += q0[j<<6];
            }
            float* vs = (br==0)?v0:(br==1)?v1:v2;
            uint32_t words[12];
#pragma unroll
            for (int j=0;j<6;j++){
                int o = (j<<6) + lane;
                float val = ((ya[j]+yb[j])+(yc[j]+yd[j]))*scLDS[br*C_+o] + shLDS[br*C_+o];
                float vv = vs[j];
                vv = vv + (val - vv)*0.5f;
                int s = (vv >= 1.0f);
                unsigned long long bal = __ballot(s);
                if (s) vv = 0.f;
                vs[j] = vv;
                words[2*j]   = (uint32_t)bal;
                words[2*j+1] = (uint32_t)(bal>>32);
            }
            if (lane == 0){
                uint32_t* mo = (br==0)?moQ:(br==1)?moK:moV;
                uint4* o4 = (uint4*)(mo + pix*NW);
                o4[0] = make_uint4(words[0],words[1],words[2],words[3]);
                o4[1] = make_uint4(words[4],words[5],words[6],words[7]);
                o4[2] = make_uint4(words[8],words[9],words[10],words[11]);
            }
        }
        __syncthreads();     // lst reused next t
    }
}

// ---------------------------------------------------------------------------
// K6a: attention counts via C = K^T V (exact integers), one block per (tb,h).
// Writes a[(tb*8+h)][n][24 u32] = 48 packed u16 counts per token.
__global__ __launch_bounds__(256) void attn_O(const uint32_t* __restrict__ mq,
                                              const uint32_t* __restrict__ mk,
                                              const uint32_t* __restrict__ mv,
                                              uint32_t* __restrict__ aCnt){
    __shared__ unsigned long long kT[DH][4];
    __shared__ unsigned long long vT[DH][4];
    __shared__ uint32_t Cp[DH*25];           // u16-pair packed C, row stride 25

    int h  = blockIdx.x & 7;
    int tb = blockIdx.x >> 3;
    int tid = threadIdx.x, wv = tid>>6, lane = tid&63;
    int sw  = (h*DH) >> 5;
    int shf = (h*DH) & 31;                   // 0 or 16

    unsigned long long q = 0, kk = 0, vvv = 0;
    if (tid < N_){
        const uint32_t* pq = mq + ((size_t)tb*N_ + tid)*NW + sw;
        const uint32_t* pk = mk + ((size_t)tb*N_ + tid)*NW + sw;
        const uint32_t* pv = mv + ((size_t)tb*N_ + tid)*NW + sw;
        unsigned long long lo, hi;
        lo = pq[0]; hi = pq[1];
        q   = (shf ? ((lo>>16) | (hi<<16)) : (lo | (hi<<32))) & 0xFFFFFFFFFFFFULL;
        lo = pk[0]; hi = pk[1];
        kk  = (shf ? ((lo>>16) | (hi<<16)) : (lo | (hi<<32))) & 0xFFFFFFFFFFFFULL;
        lo = pv[0]; hi = pv[1];
        vvv = (shf ? ((lo>>16) | (hi<<16)) : (lo | (hi<<32))) & 0xFFFFFFFFFFFFULL;
    }
#pragma unroll 1
    for (int d=0; d<DH; d++){
        unsigned long long bk_ = __ballot((int)((kk >>d)&1ull));
        unsigned long long bv_ = __ballot((int)((vvv>>d)&1ull));
        if (lane == 0){ kT[d][wv] = bk_; vT[d][wv] = bv_; }
    }
    __syncthreads();

    if (tid < 240){
        int j  = tid / 5;
        int dg = tid % 5;
        int d0 = dg*10;
        int d1 = (dg==4) ? 48 : d0+10;
        unsigned long long ka=kT[j][0], kb=kT[j][1], kc=kT[j][2], kd=kT[j][3];
        for (int d=d0; d<d1; d+=2){
            uint32_t c0 = (uint32_t)(__popcll(ka&vT[d][0]) + __popcll(kb&vT[d][1])
                        + __popcll(kc&vT[d][2]) + __popcll(kd&vT[d][3]));
            uint32_t c1 = (uint32_t)(__popcll(ka&vT[d+1][0]) + __popcll(kb&vT[d+1][1])
                        + __popcll(kc&vT[d+1][2]) + __popcll(kd&vT[d+1][3]));
            Cp[j*25 + (d>>1)] = c0 | (c1<<16);
        }
    }
    __syncthreads();

    if (tid < N_){
        uint32_t acc[24];
#pragma unroll
        for (int p=0;p<24;p++) acc[p] = 0u;
        unsigned long long qb = q;
        while (qb){
            int j = __builtin_ctzll(qb); qb &= qb-1;
            const uint32_t* row = &Cp[j*25];
#pragma unroll
            for (int p=0;p<24;p++) acc[p] += row[p];
        }
        uint4* ap = (uint4*)(aCnt + (((size_t)tb*NH + h)*N_ + tid)*24);
        ap[0] = make_uint4(acc[0], acc[1], acc[2], acc[3]);
        ap[1] = make_uint4(acc[4], acc[5], acc[6], acc[7]);
        ap[2] = make_uint4(acc[8], acc[9], acc[10],acc[11]);
        ap[3] = make_uint4(acc[12],acc[13],acc[14],acc[15]);
        ap[4] = make_uint4(acc[16],acc[17],acc[18],acc[19]);
        ap[5] = make_uint4(acc[20],acc[21],acc[22],acc[23]);
    }
}

// ---------------------------------------------------------------------------
// K6b: attn LIF over counts (vth=0.5) -> mo u16 spikes + fused bit-transpose
// into maskT_OL. Block = 1 wave: lane = pixel in group pg; c16 = 16-ch slice.
__global__ __launch_bounds__(64) void attn_lif(const uint32_t* __restrict__ aCnt,
                                               uint16_t* __restrict__ mo,
                                               unsigned long long* __restrict__ maskT){
    int pg  = blockIdx.x;                 // 0..195
    int c16 = blockIdx.y;                 // 0..23
    int lane = threadIdx.x;
    int pix0 = pg*64 + lane;              // (b,n) index, 196*64 = 12544 exact
    int b = pix0 / N_;
    int n = pix0 - b*N_;
    int h = c16 / 3, sub = c16 - h*3;
    float vm[16];
#pragma unroll
    for (int cc=0;cc<16;cc++) vm[cc] = 0.f;
#pragma unroll
    for (int t=0;t<T_;t++){
        int tb = t*B_ + b;
        const uint4* ap = (const uint4*)(aCnt + (((size_t)tb*NH + h)*N_ + n)*24 + sub*8);
        uint4 A = ap[0], Bv = ap[1];
        uint32_t cw[8] = {A.x,A.y,A.z,A.w, Bv.x,Bv.y,Bv.z,Bv.w};
        uint32_t bits = 0;
#pragma unroll
        for (int cc=0;cc<16;cc++){
            uint32_t a = (cc&1) ? (cw[cc>>1]>>16) : (cw[cc>>1]&0xFFFFu);
            float o = 0.125f*(float)a;
            vm[cc] = vm[cc] + (o - vm[cc])*0.5f;
            if (vm[cc] >= 0.5f){ bits |= (1u<<cc); vm[cc] = 0.f; }
        }
        mo[((size_t)t*P_ + pix0)*24 + c16] = (uint16_t)bits;
        int g = t*196 + pg, kc = g/12, kw = g - kc*12;
#pragma unroll
        for (int cc=0;cc<16;cc++){
            unsigned long long bal = __ballot((int)((bits>>cc)&1u));
            if (lane == 0)
                maskT[((size_t)kc*C_ + c16*16 + cc)*12 + kw] = bal;
        }
    }
}

// ---------------------------------------------------------------------------
// K7: proj conv + BN normalize + transposed write via LDS tile.
__global__ __launch_bounds__(256) void proj_out(const uint32_t* __restrict__ mask,
                                                const float* __restrict__ WT,
                                                const float* __restrict__ scale,
                                                const float* __restrict__ shift,
                                                float* __restrict__ out){
    __shared__ float tile[192][49];
    __shared__ uint16_t lst[4][392];
    int bid = blockIdx.x;
    int tb = bid>>3, r7 = bid&7, nq = r7>>1, ch = r7&1;
    int n0 = nq*49, c0 = ch*192;
    int tid = threadIdx.x, wave = tid>>6, lane = tid&63;
    float sc[3], sh[3];
#pragma unroll
    for (int i=0;i<3;i++){
        sc[i] = scale[c0+(i<<6)+lane];
        sh[i] = shift[c0+(i<<6)+lane];
    }
    for (int p=wave; p<49; p+=4){
        size_t pix = (size_t)tb*N_ + n0 + p;
        const uint4* m4 = (const uint4*)(mask + pix*NW);
        uint4 ma = m4[0], mb = m4[1], mc = m4[2];
        uint32_t mwv[12] = {ma.x,ma.y,ma.z,ma.w, mb.x,mb.y,mb.z,mb.w, mc.x,mc.y,mc.z,mc.w};
        int cnt = 0;
#pragma unroll
        for (int w=0;w<12;w++) cnt += __popc(mwv[w]);
        if (lane < 12){
            int off = 0;
            uint32_t mybits = 0;
#pragma unroll
            for (int w=0;w<12;w++){
                if (w < lane) off += __popc(mwv[w]);
                if (w == lane) mybits = mwv[w];
            }
            while (mybits){
                lst[wave][off++] = (uint16_t)((lane<<5) + __builtin_ctz(mybits));
                mybits &= mybits - 1;
            }
        }
        float ya[3]={0,0,0}, yb[3]={0,0,0}, yc[3]={0,0,0}, yd[3]={0,0,0};
        int i = 0;
        for (; i+3 < cnt; i += 4){
            ushort4 cs = *(const ushort4*)&lst[wave][i];
            const float* q0 = WT + (size_t)cs.x*C_ + c0 + lane;
            const float* q1 = WT + (size_t)cs.y*C_ + c0 + lane;
            const float* q2 = WT + (size_t)cs.z*C_ + c0 + lane;
            const float* q3 = WT + (size_t)cs.w*C_ + c0 + lane;
#pragma unroll
            for (int j=0;j<3;j++){
                ya[j] += q0[j<<6]; yb[j] += q1[j<<6];
                yc[j] += q2[j<<6]; yd[j] += q3[j<<6];
            }
        }
        for (; i < cnt; ++i){
            int c = lst[wave][i];
            const float* q0 = WT + (size_t)c*C_ + c0 + lane;
#pragma unroll
            for (int j=0;j<3;j++) ya[j] += q0[j<<6];
        }
#pragma unroll
        for (int j=0;j<3;j++)
            tile[(j<<6)+lane][p] = ((ya[j]+yb[j])+(yc[j]+yd[j]))*sc[j] + sh[j];
    }
    __syncthreads();
    for (int r=wave; r<192; r+=4){
        if (lane < 49)
            out[((size_t)tb*C_ + c0 + r)*N_ + n0 + lane] = tile[r][lane];
    }
}

// ---------------------------------------------------------------------------
extern "C" void kernel_launch(void* const* d_in, const int* in_sizes, int n_in,
                              void* d_out, int out_size, void* d_ws, size_t ws_size,
                              hipStream_t stream) {
    const float* x  = (const float*)d_in[0];
    const float* Wq = (const float*)d_in[1];
    const float* Wk = (const float*)d_in[2];
    const float* Wv = (const float*)d_in[3];
    const float* Wp = (const float*)d_in[4];
    const float* gq = (const float*)d_in[5];
    const float* bq = (const float*)d_in[6];
    const float* gk = (const float*)d_in[7];
    const float* bk = (const float*)d_in[8];
    const float* gv = (const float*)d_in[9];
    const float* bv = (const float*)d_in[10];
    const float* gp = (const float*)d_in[11];
    const float* bp = (const float*)d_in[12];

    // workspace carve (~57 MB)
    char* w = (char*)d_ws;
    size_t off = 0;
    uint32_t* maskXS = (uint32_t*)(w + off); off += (size_t)R_*NW*4;   // 2.41 MB each
    uint32_t* maskQ  = (uint32_t*)(w + off); off += (size_t)R_*NW*4;
    uint32_t* maskK  = (uint32_t*)(w + off); off += (size_t)R_*NW*4;
    uint32_t* maskV  = (uint32_t*)(w + off); off += (size_t)R_*NW*4;
    float* WTall = (float*)(w + off); off += (size_t)4*C_*C_*4;        // 2.36 MB
    // zero-init region: [maskT_XS][maskT_OL][GuXS][GuOL] (one memset)
    unsigned long long* maskTX = (unsigned long long*)(w + off); off += (size_t)NCHX*C_*12*8; // 3.17 MB
    unsigned long long* maskTO = (unsigned long long*)(w + off); off += (size_t)NCHO*C_*12*8; // 2.43 MB
    unsigned int* GuX = (unsigned int*)(w + off); off += (size_t)C_*C_*4;  // 0.59 MB
    unsigned int* GuO = (unsigned int*)(w + off); off += (size_t)C_*C_*4;
    size_t zbytes = (size_t)NCHX*C_*12*8 + (size_t)NCHO*C_*12*8 + 2*(size_t)C_*C_*4;
    uint32_t* aCnt = (uint32_t*)(w + off); off += (size_t)R_*NH*24*4;  // 38.5 MB
    float* scaleB = (float*)(w + off); off += (size_t)4*C_*4;
    float* shiftB = (float*)(w + off); off += (size_t)4*C_*4;
    uint32_t* maskOL = maskXS;      // alias: XS dead after conv_lif3

    hipMemsetAsync(maskTX, 0, zbytes, stream);

    transpose_w4<<<dim3(6,6,4),256,0,stream>>>(Wq, Wk, Wv, Wp, WTall);

    pre_lif<<<B_*NW,256,0,stream>>>(x, maskXS, maskTX);

    gram<<<dim3((NCHX+3)/4,6,8),256,0,stream>>>(maskTX, GuX, NCHX);
    bn_from_gram<<<dim3(96,3),384,0,stream>>>(GuX, WTall, gq,bq, gk,bk, gv,bv,
                                              scaleB, shiftB, 0);

    conv_lif3<<<P_/4,256,0,stream>>>(maskXS, WTall, scaleB, shiftB,
                                     maskQ, maskK, maskV);

    attn_O<<<TB_*NH,256,0,stream>>>(maskQ, maskK, maskV, aCnt);
    attn_lif<<<dim3(196,24),64,0,stream>>>(aCnt, (uint16_t*)maskOL, maskTO);

    gram<<<dim3((NCHO+3)/4,6,8),256,0,stream>>>(maskTO, GuO, NCHO);
    bn_from_gram<<<dim3(96,1),384,0,stream>>>(GuO, WTall, gp,bp, gp,bp, gp,bp,
                                              scaleB + 3*C_, shiftB + 3*C_, 3);

    proj_out<<<TB_*8,256,0,stream>>>(maskOL, WTall + (size_t)3*C_*C_,
                                     scaleB + 3*C_, shiftB + 3*C_, (float*)d_out);
}

// Round 12
// 360.391 us; speedup vs baseline: 1.5401x; 1.0442x over previous
//
#include <hip/hip_runtime.h>
#include <hip/hip_bf16.h>
#include <stdint.h>

// Shapes (hard-coded for this problem)
#define T_  4
#define B_  64
#define C_  384
#define N_  196        // H*W = 14*14
#define NH  8
#define DH  48
#define TB_ (T_*B_)          // 256
#define R_  (T_*B_*N_)       // 50176 pixels total
#define NW  12               // 384 bits -> 12 u32 words per pixel
#define P_  12544            // B_*N_ pixels per timestep
#define NCHX 86              // XS chunks: 1024 groups (tb*4+wave), padded
#define NCHO 66              // OL chunks: 784 groups (t*196+pg), exact+8 pad words
#define NZBLK 414            // zero blocks: 414*256*4 uint4 = 6,782,976 B exactly

typedef float f32x2 __attribute__((ext_vector_type(2)));

// ---------------------------------------------------------------------------
// K0: fused prep — blocks [0,144): LDS-tiled transpose W[o][c] -> WT[m][c][o];
// blocks [144,144+NZBLK): zero the [maskTX][maskTO][GuX][GuO] region.
__global__ __launch_bounds__(256) void prep(const float* __restrict__ s0,
        const float* __restrict__ s1, const float* __restrict__ s2,
        const float* __restrict__ s3, float* __restrict__ dst,
        uint4* __restrict__ zbase){
    int blk = blockIdx.x;
    if (blk >= 144){
        int z = blk - 144;
        uint4* p = zbase + (size_t)z*1024 + (size_t)threadIdx.x*4;
        uint4 zero = make_uint4(0,0,0,0);
        p[0]=zero; p[1]=zero; p[2]=zero; p[3]=zero;
        return;
    }
    __shared__ float tile[64][65];
    int m = blk/36, rem = blk%36;
    const float* src = (m==0)?s0:(m==1)?s1:(m==2)?s2:s3;
    int o0 = (rem/6)*64, c0 = (rem%6)*64;
    int lane = threadIdx.x & 63, w = threadIdx.x >> 6;
    for (int r = w; r < 64; r += 4)
        tile[r][lane] = src[(size_t)(o0+r)*C_ + c0 + lane];
    __syncthreads();
    for (int r = w; r < 64; r += 4)
        dst[(size_t)m*C_*C_ + (size_t)(c0+r)*C_ + o0 + lane] = tile[lane][r];
}

// ---------------------------------------------------------------------------
// K1: pre-LIF on raw x -> spike bitmask + fused bit-transpose into maskT_XS.
__global__ __launch_bounds__(256) void pre_lif(const float* __restrict__ x,
                                               uint32_t* __restrict__ maskXS,
                                               unsigned long long* __restrict__ maskT){
    int b = blockIdx.x / NW;
    int w = blockIdx.x % NW;
    int n = threadIdx.x;
    if (n >= N_) return;
    int wv = n >> 6, lane = n & 63;
    float v[32];
#pragma unroll
    for (int j=0;j<32;j++) v[j] = 0.f;
#pragma unroll
    for (int t=0;t<T_;t++){
        int tb = t*B_ + b;
        uint32_t word = 0;
#pragma unroll
        for (int j=0;j<32;j++){
            int c = w*32 + j;
            float xv = x[((size_t)tb*C_ + c)*N_ + n];
            v[j] = v[j] + (xv - v[j])*0.5f;
            if (v[j] >= 1.0f){ word |= (1u<<j); v[j] = 0.f; }
        }
        maskXS[((size_t)tb*N_ + n)*NW + w] = word;
        int g = tb*4 + wv, kc = g/12, kw = g - kc*12;
#pragma unroll
        for (int j=0;j<32;j++){
            unsigned long long bal = __ballot((int)((word>>j)&1u));
            if (lane == 0)
                maskT[((size_t)kc*C_ + (w*32+j))*12 + kw] = bal;
        }
    }
}

// ---------------------------------------------------------------------------
// K3: Gram: G[c][c'] popcount co-occurrence into global u32 Gu (exact).
__global__ __launch_bounds__(256) void gram(const unsigned long long* __restrict__ maskT,
                                            unsigned int* __restrict__ Gu, int nch){
    __shared__ unsigned int tile[64][49];
    int tid = threadIdx.x, wave = tid>>6, lane = tid&63;
    int kg = blockIdx.x, rg = blockIdx.y, cg = blockIdx.z;
    for (int i=tid; i<64*49; i+=256) ((unsigned int*)tile)[i] = 0u;
    __syncthreads();
    int kc = kg*4 + wave;
    if (kc < nch){
        const uint4* rp = (const uint4*)(maskT + ((size_t)kc*C_ + rg*64 + lane)*12);
        uint32_t row[24];
#pragma unroll
        for (int q=0;q<6;q++){
            uint4 a = rp[q];
            row[4*q]=a.x; row[4*q+1]=a.y; row[4*q+2]=a.z; row[4*q+3]=a.w;
        }
        for (int cc=0; cc<48; cc++){
            const uint4* cp = (const uint4*)(maskT + ((size_t)kc*C_ + cg*48 + cc)*12);
            uint32_t col[24];
#pragma unroll
            for (int q=0;q<6;q++){
                uint4 a = cp[q];
                col[4*q]=a.x; col[4*q+1]=a.y; col[4*q+2]=a.z; col[4*q+3]=a.w;
            }
            unsigned int s = 0;
#pragma unroll
            for (int q=0;q<24;q++) s += (unsigned int)__popc(row[q]&col[q]);
            atomicAdd(&tile[lane][cc], s);
        }
    }
    __syncthreads();
    for (int i=tid; i<64*48; i+=256){
        int r = i/48, cc = i%48;
        unsigned int v = tile[r][cc];
        if (v) atomicAdd(&Gu[(size_t)(rg*64+r)*C_ + cg*48 + cc], v);
    }
}

// ---------------------------------------------------------------------------
// K4: BN scale/shift from Gram: sum[o]=sum_c cnt[c] w[c], sumsq[o]=w^T G w.
__global__ __launch_bounds__(384) void bn_from_gram(const unsigned int* __restrict__ Gu,
        const float* __restrict__ WTall,
        const float* __restrict__ g0, const float* __restrict__ b0,
        const float* __restrict__ g1, const float* __restrict__ b1,
        const float* __restrict__ g2, const float* __restrict__ b2,
        float* __restrict__ scaleOut, float* __restrict__ shiftOut, int wtBase){
    __shared__ float w4[384][4];
    __shared__ float sred[8][6];
    int t = threadIdx.x, wave = t>>6, lane = t&63;
    int br = blockIdx.y;
    const float* WT = WTall + (size_t)(wtBase+br)*C_*C_;
    int o0 = blockIdx.x*4;
    float4 wv = *(const float4*)(WT + (size_t)t*C_ + o0);
    w4[t][0]=wv.x; w4[t][1]=wv.y; w4[t][2]=wv.z; w4[t][3]=wv.w;
    __syncthreads();
    float h0=0.f,h1=0.f,h2=0.f,h3=0.f;
#pragma unroll 8
    for (int c=0;c<C_;c++){
        float gv = (float)Gu[(size_t)c*C_ + t];
        float4 wc = *(const float4*)&w4[c][0];
        h0 += gv*wc.x; h1 += gv*wc.y; h2 += gv*wc.z; h3 += gv*wc.w;
    }
    float cnt = (float)Gu[(size_t)t*C_ + t];
    float p0=wv.x*h0, p1=wv.y*h1, p2=wv.z*h2, p3=wv.w*h3;
    float q0=cnt*wv.x, q1=cnt*wv.y, q2=cnt*wv.z, q3=cnt*wv.w;
#pragma unroll
    for (int off=32; off>0; off>>=1){
        p0+=__shfl_down(p0,off); p1+=__shfl_down(p1,off);
        p2+=__shfl_down(p2,off); p3+=__shfl_down(p3,off);
        q0+=__shfl_down(q0,off); q1+=__shfl_down(q1,off);
        q2+=__shfl_down(q2,off); q3+=__shfl_down(q3,off);
    }
    if (lane == 0){
        sred[0][wave]=p0; sred[1][wave]=p1; sred[2][wave]=p2; sred[3][wave]=p3;
        sred[4][wave]=q0; sred[5][wave]=q1; sred[6][wave]=q2; sred[7][wave]=q3;
    }
    __syncthreads();
    if (t < 4){
        const float* g  = (br==0)?g0:(br==1)?g1:g2;
        const float* bb = (br==0)?b0:(br==1)?b1:b2;
        float ss = ((sred[t][0]+sred[t][1])+(sred[t][2]+sred[t][3]))+(sred[t][4]+sred[t][5]);
        float sm = ((sred[4+t][0]+sred[4+t][1])+(sred[4+t][2]+sred[4+t][3]))+(sred[4+t][4]+sred[4+t][5]);
        float m   = sm / (float)R_;
        float var = ss / (float)R_ - m*m;
        float sc  = g[o0+t] / sqrtf(var + 1e-5f);
        scaleOut[br*C_ + o0+t] = sc;
        shiftOut[br*C_ + o0+t] = bb[o0+t] - m*sc;
    }
}

// ---------------------------------------------------------------------------
// K5: sparse conv + fused BN + LIF + pack, ONE branch per dispatch (diagnostic
// split of the L2-roofline conv: same total traffic, cutoff drops to ~42 us).
__global__ __launch_bounds__(256) void conv_lif_b(const uint32_t* __restrict__ mask,
        const float* __restrict__ WTbr,
        const float* __restrict__ scale, const float* __restrict__ shift,
        uint32_t* __restrict__ mo){
    __shared__ uint16_t lst[4][416];
    __shared__ float scLDS[C_];
    __shared__ float shLDS[C_];
    int tid = threadIdx.x, wave = tid>>6, lane = tid&63;
    int pix0 = blockIdx.x*4 + wave;
    for (int i=tid; i<C_; i+=256){ scLDS[i]=scale[i]; shLDS[i]=shift[i]; }
    __syncthreads();

    float vs[6]={0,0,0,0,0,0};
    for (int t=0;t<T_;t++){
        size_t pix = (size_t)t*P_ + pix0;
        const uint4* m4 = (const uint4*)(mask + pix*NW);
        uint4 ma = m4[0], mb = m4[1], mc = m4[2];       // wave-uniform
        uint32_t mwv[12] = {ma.x,ma.y,ma.z,ma.w, mb.x,mb.y,mb.z,mb.w, mc.x,mc.y,mc.z,mc.w};
        int cnt = 0;
#pragma unroll
        for (int w=0;w<12;w++) cnt += __popc(mwv[w]);
        if (lane < 12){
            int off = 0;
            uint32_t mybits = 0;
#pragma unroll
            for (int w=0;w<12;w++){
                if (w < lane) off += __popc(mwv[w]);
                if (w == lane) mybits = mwv[w];
            }
            while (mybits){
                lst[wave][off++] = (uint16_t)((lane<<5) + __builtin_ctz(mybits));
                mybits &= mybits - 1;
            }
        }
        __syncthreads();

        const float* WT = WTbr + lane;
        float ya[6]={0,0,0,0,0,0}, yb[6]={0,0,0,0,0,0};
        float yc[6]={0,0,0,0,0,0}, yd[6]={0,0,0,0,0,0};
        int i = 0;
        for (; i+3 < cnt; i += 4){
            ushort4 cs = *(const ushort4*)&lst[wave][i];
            const float* q0 = WT + (size_t)cs.x*C_;
            const float* q1 = WT + (size_t)cs.y*C_;
            const float* q2 = WT + (size_t)cs.z*C_;
            const float* q3 = WT + (size_t)cs.w*C_;
#pragma unroll
            for (int j=0;j<6;j++){
                ya[j] += q0[j<<6]; yb[j] += q1[j<<6];
                yc[j] += q2[j<<6]; yd[j] += q3[j<<6];
            }
        }
        for (; i < cnt; ++i){
            int c = lst[wave][i];
            const float* q0 = WT + (size_t)c*C_;
#pragma unroll
            for (int j=0;j<6;j++) ya[j] += q0[j<<6];
        }
        uint32_t words[12];
#pragma unroll
        for (int j=0;j<6;j++){
            int o = (j<<6) + lane;
            float val = ((ya[j]+yb[j])+(yc[j]+yd[j]))*scLDS[o] + shLDS[o];
            float vv = vs[j];
            vv = vv + (val - vv)*0.5f;
            int s = (vv >= 1.0f);
            unsigned long long bal = __ballot(s);
            if (s) vv = 0.f;
            vs[j] = vv;
            words[2*j]   = (uint32_t)bal;
            words[2*j+1] = (uint32_t)(bal>>32);
        }
        if (lane == 0){
            uint4* o4 = (uint4*)(mo + pix*NW);
            o4[0] = make_uint4(words[0],words[1],words[2],words[3]);
            o4[1] = make_uint4(words[4],words[5],words[6],words[7]);
            o4[2] = make_uint4(words[8],words[9],words[10],words[11]);
        }
        __syncthreads();     // lst reused next t
    }
}

// ---------------------------------------------------------------------------
// K6a: attention counts via C = K^T V (exact integers), one block per (tb,h).
// aCnt layout: [tb][h][sub(3)][n][8 u32] -> coalesced writes AND reads.
__global__ __launch_bounds__(256) void attn_O(const uint32_t* __restrict__ mq,
                                              const uint32_t* __restrict__ mk,
                                              const uint32_t* __restrict__ mv,
                                              uint32_t* __restrict__ aCnt){
    __shared__ unsigned long long kT[DH][4];
    __shared__ unsigned long long vT[DH][4];
    __shared__ uint32_t Cp[DH*25];           // u16-pair packed C, row stride 25

    int h  = blockIdx.x & 7;
    int tb = blockIdx.x >> 3;
    int tid = threadIdx.x, wv = tid>>6, lane = tid&63;
    int sw  = (h*DH) >> 5;
    int shf = (h*DH) & 31;                   // 0 or 16

    unsigned long long q = 0, kk = 0, vvv = 0;
    if (tid < N_){
        const uint32_t* pq = mq + ((size_t)tb*N_ + tid)*NW + sw;
        const uint32_t* pk = mk + ((size_t)tb*N_ + tid)*NW + sw;
        const uint32_t* pv = mv + ((size_t)tb*N_ + tid)*NW + sw;
        unsigned long long lo, hi;
        lo = pq[0]; hi = pq[1];
        q   = (shf ? ((lo>>16) | (hi<<16)) : (lo | (hi<<32))) & 0xFFFFFFFFFFFFULL;
        lo = pk[0]; hi = pk[1];
        kk  = (shf ? ((lo>>16) | (hi<<16)) : (lo | (hi<<32))) & 0xFFFFFFFFFFFFULL;
        lo = pv[0]; hi = pv[1];
        vvv = (shf ? ((lo>>16) | (hi<<16)) : (lo | (hi<<32))) & 0xFFFFFFFFFFFFULL;
    }
#pragma unroll 1
    for (int d=0; d<DH; d++){
        unsigned long long bk_ = __ballot((int)((kk >>d)&1ull));
        unsigned long long bv_ = __ballot((int)((vvv>>d)&1ull));
        if (lane == 0){ kT[d][wv] = bk_; vT[d][wv] = bv_; }
    }
    __syncthreads();

    if (tid < 240){
        int j  = tid / 5;
        int dg = tid % 5;
        int d0 = dg*10;
        int d1 = (dg==4) ? 48 : d0+10;
        unsigned long long ka=kT[j][0], kb=kT[j][1], kc=kT[j][2], kd=kT[j][3];
        for (int d=d0; d<d1; d+=2){
            uint32_t c0 = (uint32_t)(__popcll(ka&vT[d][0]) + __popcll(kb&vT[d][1])
                        + __popcll(kc&vT[d][2]) + __popcll(kd&vT[d][3]));
            uint32_t c1 = (uint32_t)(__popcll(ka&vT[d+1][0]) + __popcll(kb&vT[d+1][1])
                        + __popcll(kc&vT[d+1][2]) + __popcll(kd&vT[d+1][3]));
            Cp[j*25 + (d>>1)] = c0 | (c1<<16);
        }
    }
    __syncthreads();

    if (tid < N_){
        uint32_t acc[24];
#pragma unroll
        for (int p=0;p<24;p++) acc[p] = 0u;
        unsigned long long qb = q;
        while (qb){
            int j = __builtin_ctzll(qb); qb &= qb-1;
            const uint32_t* row = &Cp[j*25];
#pragma unroll
            for (int p=0;p<24;p++) acc[p] += row[p];
        }
        size_t hb = ((size_t)tb*NH + h)*3;
#pragma unroll
        for (int sub=0; sub<3; ++sub){
            uint4* ap = (uint4*)(aCnt + ((hb + sub)*N_ + tid)*8);
            ap[0] = make_uint4(acc[sub*8+0], acc[sub*8+1], acc[sub*8+2], acc[sub*8+3]);
            ap[1] = make_uint4(acc[sub*8+4], acc[sub*8+5], acc[sub*8+6], acc[sub*8+7]);
        }
    }
}

// ---------------------------------------------------------------------------
// K6b: attn LIF over counts (vth=0.5) -> mo u16 spikes + fused bit-transpose
// into maskT_OL. Block = 1 wave: lane = pixel in group pg; c16 = 16-ch slice.
__global__ __launch_bounds__(64) void attn_lif(const uint32_t* __restrict__ aCnt,
                                               uint16_t* __restrict__ mo,
                                               unsigned long long* __restrict__ maskT){
    int pg  = blockIdx.x;                 // 0..195
    int c16 = blockIdx.y;                 // 0..23
    int lane = threadIdx.x;
    int pix0 = pg*64 + lane;              // (b,n) index, 196*64 = 12544 exact
    int b = pix0 / N_;
    int n = pix0 - b*N_;
    int h = c16 / 3, sub = c16 - h*3;
    float vm[16];
#pragma unroll
    for (int cc=0;cc<16;cc++) vm[cc] = 0.f;
#pragma unroll
    for (int t=0;t<T_;t++){
        int tb = t*B_ + b;
        const uint4* ap = (const uint4*)(aCnt + ((((size_t)tb*NH + h)*3 + sub)*N_ + n)*8);
        uint4 A = ap[0], Bv = ap[1];
        uint32_t cw[8] = {A.x,A.y,A.z,A.w, Bv.x,Bv.y,Bv.z,Bv.w};
        uint32_t bits = 0;
#pragma unroll
        for (int cc=0;cc<16;cc++){
            uint32_t a = (cc&1) ? (cw[cc>>1]>>16) : (cw[cc>>1]&0xFFFFu);
            float o = 0.125f*(float)a;
            vm[cc] = vm[cc] + (o - vm[cc])*0.5f;
            if (vm[cc] >= 0.5f){ bits |= (1u<<cc); vm[cc] = 0.f; }
        }
        mo[((size_t)t*P_ + pix0)*24 + c16] = (uint16_t)bits;
        int g = t*196 + pg, kc = g/12, kw = g - kc*12;
#pragma unroll
        for (int cc=0;cc<16;cc++){
            unsigned long long bal = __ballot((int)((bits>>cc)&1u));
            if (lane == 0)
                maskT[((size_t)kc*C_ + c16*16 + cc)*12 + kw] = bal;
        }
    }
}

// ---------------------------------------------------------------------------
// K7: proj conv + BN normalize + transposed write via LDS tile.
__global__ __launch_bounds__(256) void proj_out(const uint32_t* __restrict__ mask,
                                                const float* __restrict__ WT,
                                                const float* __restrict__ scale,
                                                const float* __restrict__ shift,
                                                float* __restrict__ out){
    __shared__ float tile[192][49];
    __shared__ uint16_t lst[4][392];
    int bid = blockIdx.x;
    int tb = bid>>3, r7 = bid&7, nq = r7>>1, ch = r7&1;
    int n0 = nq*49, c0 = ch*192;
    int tid = threadIdx.x, wave = tid>>6, lane = tid&63;
    float sc[3], sh[3];
#pragma unroll
    for (int i=0;i<3;i++){
        sc[i] = scale[c0+(i<<6)+lane];
        sh[i] = shift[c0+(i<<6)+lane];
    }
    for (int p=wave; p<49; p+=4){
        size_t pix = (size_t)tb*N_ + n0 + p;
        const uint4* m4 = (const uint4*)(mask + pix*NW);
        uint4 ma = m4[0], mb = m4[1], mc = m4[2];
        uint32_t mwv[12] = {ma.x,ma.y,ma.z,ma.w, mb.x,mb.y,mb.z,mb.w, mc.x,mc.y,mc.z,mc.w};
        int cnt = 0;
#pragma unroll
        for (int w=0;w<12;w++) cnt += __popc(mwv[w]);
        if (lane < 12){
            int off = 0;
            uint32_t mybits = 0;
#pragma unroll
            for (int w=0;w<12;w++){
                if (w < lane) off += __popc(mwv[w]);
                if (w == lane) mybits = mwv[w];
            }
            while (mybits){
                lst[wave][off++] = (uint16_t)((lane<<5) + __builtin_ctz(mybits));
                mybits &= mybits - 1;
            }
        }
        float ya[3]={0,0,0}, yb[3]={0,0,0}, yc[3]={0,0,0}, yd[3]={0,0,0};
        int i = 0;
        for (; i+3 < cnt; i += 4){
            ushort4 cs = *(const ushort4*)&lst[wave][i];
            const float* q0 = WT + (size_t)cs.x*C_ + c0 + lane;
            const float* q1 = WT + (size_t)cs.y*C_ + c0 + lane;
            const float* q2 = WT + (size_t)cs.z*C_ + c0 + lane;
            const float* q3 = WT + (size_t)cs.w*C_ + c0 + lane;
#pragma unroll
            for (int j=0;j<3;j++){
                ya[j] += q0[j<<6]; yb[j] += q1[j<<6];
                yc[j] += q2[j<<6]; yd[j] += q3[j<<6];
            }
        }
        for (; i < cnt; ++i){
            int c = lst[wave][i];
            const float* q0 = WT + (size_t)c*C_ + c0 + lane;
#pragma unroll
            for (int j=0;j<3;j++) ya[j] += q0[j<<6];
        }
#pragma unroll
        for (int j=0;j<3;j++)
            tile[(j<<6)+lane][p] = ((ya[j]+yb[j])+(yc[j]+yd[j]))*sc[j] + sh[j];
    }
    __syncthreads();
    for (int r=wave; r<192; r+=4){
        if (lane < 49)
            out[((size_t)tb*C_ + c0 + r)*N_ + n0 + lane] = tile[r][lane];
    }
}

// ---------------------------------------------------------------------------
extern "C" void kernel_launch(void* const* d_in, const int* in_sizes, int n_in,
                              void* d_out, int out_size, void* d_ws, size_t ws_size,
                              hipStream_t stream) {
    const float* x  = (const float*)d_in[0];
    const float* Wq = (const float*)d_in[1];
    const float* Wk = (const float*)d_in[2];
    const float* Wv = (const float*)d_in[3];
    const float* Wp = (const float*)d_in[4];
    const float* gq = (const float*)d_in[5];
    const float* bq = (const float*)d_in[6];
    const float* gk = (const float*)d_in[7];
    const float* bk = (const float*)d_in[8];
    const float* gv = (const float*)d_in[9];
    const float* bv = (const float*)d_in[10];
    const float* gp = (const float*)d_in[11];
    const float* bp = (const float*)d_in[12];

    // workspace carve (~57 MB)
    char* w = (char*)d_ws;
    size_t off = 0;
    uint32_t* maskXS = (uint32_t*)(w + off); off += (size_t)R_*NW*4;   // 2.41 MB each
    uint32_t* maskQ  = (uint32_t*)(w + off); off += (size_t)R_*NW*4;
    uint32_t* maskK  = (uint32_t*)(w + off); off += (size_t)R_*NW*4;
    uint32_t* maskV  = (uint32_t*)(w + off); off += (size_t)R_*NW*4;
    float* WTall = (float*)(w + off); off += (size_t)4*C_*C_*4;        // 2.36 MB
    // zero-init region: [maskT_XS][maskT_OL][GuXS][GuOL] (zeroed by prep)
    unsigned long long* maskTX = (unsigned long long*)(w + off); off += (size_t)NCHX*C_*12*8; // 3.17 MB
    unsigned long long* maskTO = (unsigned long long*)(w + off); off += (size_t)NCHO*C_*12*8; // 2.43 MB
    unsigned int* GuX = (unsigned int*)(w + off); off += (size_t)C_*C_*4;  // 0.59 MB
    unsigned int* GuO = (unsigned int*)(w + off); off += (size_t)C_*C_*4;
    uint32_t* aCnt = (uint32_t*)(w + off); off += (size_t)R_*NH*24*4;  // 38.5 MB
    float* scaleB = (float*)(w + off); off += (size_t)4*C_*4;
    float* shiftB = (float*)(w + off); off += (size_t)4*C_*4;
    uint32_t* maskOL = maskXS;      // alias: XS dead after conv branches

    prep<<<144+NZBLK,256,0,stream>>>(Wq, Wk, Wv, Wp, WTall, (uint4*)maskTX);

    pre_lif<<<B_*NW,256,0,stream>>>(x, maskXS, maskTX);

    gram<<<dim3((NCHX+3)/4,6,8),256,0,stream>>>(maskTX, GuX, NCHX);
    bn_from_gram<<<dim3(96,3),384,0,stream>>>(GuX, WTall, gq,bq, gk,bk, gv,bv,
                                              scaleB, shiftB, 0);

    uint32_t* Ms[3] = {maskQ, maskK, maskV};
    for (int br=0; br<3; ++br)
        conv_lif_b<<<P_/4,256,0,stream>>>(maskXS, WTall + (size_t)br*C_*C_,
                                          scaleB + br*C_, shiftB + br*C_, Ms[br]);

    attn_O<<<TB_*NH,256,0,stream>>>(maskQ, maskK, maskV, aCnt);
    attn_lif<<<dim3(196,24),64,0,stream>>>(aCnt, (uint16_t*)maskOL, maskTO);

    gram<<<dim3((NCHO+3)/4,6,8),256,0,stream>>>(maskTO, GuO, NCHO);
    bn_from_gram<<<dim3(96,1),384,0,stream>>>(GuO, WTall, gp,bp, gp,bp, gp,bp,
                                              scaleB + 3*C_, shiftB + 3*C_, 3);

    proj_out<<<TB_*8,256,0,stream>>>(maskOL, WTall + (size_t)3*C_*C_,
                                     scaleB + 3*C_, shiftB + 3*C_, (float*)d_out);
}